// Round 3
// baseline (949.457 us; speedup 1.0000x reference)
//
#include <hip/hip_runtime.h>
#include <hip/hip_bf16.h>
#include <stdint.h>

#define B_ 4
#define S_IN 32768
#define C1V 128
#define L1V 16384
#define C2V 256
#define L2V 8192
#define C3V 512
#define L3V 4096
#define VOCABV 2048
#define KCB 4

typedef _Float16 half8 __attribute__((ext_vector_type(8)));
typedef float floatx4 __attribute__((ext_vector_type(4)));

#define AS1 __attribute__((address_space(1)))
#define AS3 __attribute__((address_space(3)))

__device__ __forceinline__ void gload_lds16(const void* g, void* l) {
    __builtin_amdgcn_global_load_lds((const AS1 void*)g, (AS3 void*)l, 16, 0, 0);
}

// read 8 halfs at a 4B-aligned LDS address (4x ds_read_b32)
__device__ __forceinline__ half8 lds_read_half8_a4(const _Float16* p) {
    union { uint32_t u[4]; half8 h; } t;
    const uint32_t* w = (const uint32_t*)p;
    t.u[0] = w[0]; t.u[1] = w[1]; t.u[2] = w[2]; t.u[3] = w[3];
    return t.h;
}

// ---------------- conv1: [B,1,S] -> [B,128,16384], k=7 s=2 p=3, relu ----------------
__global__ void conv1_kernel(const float* __restrict__ x, const float* __restrict__ w,
                             const float* __restrict__ bias, float* __restrict__ out) {
    __shared__ float xs[2 * 256 + 6];
    __shared__ float ws[7];
    const int l0 = blockIdx.x * 256;
    const int co = blockIdx.y;
    const int b  = blockIdx.z;
    const int tid = threadIdx.x;
    const float* xb = x + (size_t)b * S_IN;
    for (int n = tid; n < 2 * 256 + 6; n += 256) {
        int p = 2 * l0 - 3 + n;
        xs[n] = (p >= 0 && p < S_IN) ? xb[p] : 0.f;
    }
    if (tid < 7) ws[tid] = w[co * 7 + tid];
    __syncthreads();
    float acc = bias[co];
    const int base = 2 * tid;
#pragma unroll
    for (int t = 0; t < 7; ++t) acc = fmaf(ws[t], xs[base + t], acc);
    acc = fmaxf(acc, 0.f);
    out[((size_t)(b * C1V + co)) * L1V + l0 + tid] = acc;
}

// ---------------- weight prep: w[co][ci][7] fp32 -> hi/lo f16 planes [co][ci*8+u] ----
__global__ void wsplit_kernel(const float* __restrict__ w, _Float16* __restrict__ wh,
                              _Float16* __restrict__ wl, int cin, int cout) {
    int idx = blockIdx.x * 256 + threadIdx.x;
    if (idx >= cin * cout) return;
    int co = idx / cin;
    int ci = idx - co * cin;
    const float* src = w + ((size_t)co * cin + ci) * 7;
    half8 h, l;
    h[0] = (_Float16)0.f; l[0] = (_Float16)0.f;
#pragma unroll
    for (int u = 1; u < 8; ++u) {
        float v = src[u - 1] * 1024.f;
        _Float16 hh = (_Float16)v;
        h[u] = hh;
        l[u] = (_Float16)(v - (float)hh);
    }
    size_t o = (size_t)co * (cin * 8) + ci * 8;
    *(half8*)(wh + o) = h;
    *(half8*)(wl + o) = l;
}

// Bank-conflict fix (rule 21): LDS dest stays linear (gload_lds writes base+lane*16);
// the 16B segment of the GLOBAL source is XOR-swizzled by row bits 1..2, and the
// fragment read applies the same XOR. Involution on both sides; row%16 carries the
// XOR bits so (cl>>1)&3 at read == (row>>1)&3 at write.

// ---------------- conv2 via f16 3-product MFMA: A=W (m=co), B=X windows (n=l) -------
__global__ __launch_bounds__(256, 2) void conv2_mfma_kernel(
    const float* __restrict__ in, const _Float16* __restrict__ WH,
    const _Float16* __restrict__ WL, const float* __restrict__ bias,
    float* __restrict__ out) {
    __shared__ _Float16 XsH[4 * 272], XsL[4 * 272];
    __shared__ _Float16 WsH[128 * 32], WsL[128 * 32];
    const int tid = threadIdx.x;
    const int wave = tid >> 6;
    const int lane = tid & 63;
    const int wm = wave >> 1, wn = wave & 1;
    const int q  = lane >> 4;
    const int cl = lane & 15;
    const int l0  = blockIdx.x * 128;
    const int co0 = blockIdx.y * 128;
    const int b   = blockIdx.z;
    const float* inb = in + (size_t)b * C1V * L1V;

    const int wrow  = lane >> 2;
    const int wseg  = lane & 3;
    const int wsoff = (wseg ^ ((wrow >> 1) & 3)) * 8;   // swizzled source offset (halfs)
    const int rq    = (q ^ ((cl >> 1) & 3)) * 8;        // swizzled read offset (halfs)

    floatx4 acc[4][4];
#pragma unroll
    for (int a = 0; a < 4; ++a)
#pragma unroll
        for (int n = 0; n < 4; ++n) acc[a][n] = (floatx4){0.f, 0.f, 0.f, 0.f};

    for (int ch = 0; ch < 32; ++ch) {
        __syncthreads();
        for (int n = tid; n < 4 * 264; n += 256) {
            int ci = n / 264;
            int m  = n - ci * 264;
            int p  = 2 * l0 - 4 + m;
            float v = (p >= 0 && p < L1V) ? inb[(size_t)(ch * 4 + ci) * L1V + p] * 1024.f : 0.f;
            _Float16 h = (_Float16)v;
            XsH[ci * 272 + m] = h;
            XsL[ci * 272 + m] = (_Float16)(v - (float)h);
        }
        const int k0 = ch * 32;
        for (int g = wave; g < 8; g += 4) {
            const _Float16* gh = WH + (size_t)(co0 + g * 16 + wrow) * 1024 + k0 + wsoff;
            const _Float16* gl = WL + (size_t)(co0 + g * 16 + wrow) * 1024 + k0 + wsoff;
            gload_lds16(gh, (char*)WsH + g * 1024);
            gload_lds16(gl, (char*)WsL + g * 1024);
        }
        asm volatile("s_waitcnt vmcnt(0)" ::: "memory");
        __syncthreads();

        half8 awh[4], awl[4], bxh[4], bxl[4];
#pragma unroll
        for (int a = 0; a < 4; ++a) {
            const int ro = (wm * 64 + a * 16 + cl) * 32 + rq;
            awh[a] = *(const half8*)&WsH[ro];
            awl[a] = *(const half8*)&WsL[ro];
        }
#pragma unroll
        for (int n = 0; n < 4; ++n) {
            const int lrel = wn * 64 + n * 16 + cl;
            bxh[n] = lds_read_half8_a4(&XsH[q * 272 + 2 * lrel]);
            bxl[n] = lds_read_half8_a4(&XsL[q * 272 + 2 * lrel]);
        }
#pragma unroll
        for (int a = 0; a < 4; ++a)
#pragma unroll
            for (int n = 0; n < 4; ++n) {
                acc[a][n] = __builtin_amdgcn_mfma_f32_16x16x32_f16(awh[a], bxh[n], acc[a][n], 0, 0, 0);
                acc[a][n] = __builtin_amdgcn_mfma_f32_16x16x32_f16(awl[a], bxh[n], acc[a][n], 0, 0, 0);
                acc[a][n] = __builtin_amdgcn_mfma_f32_16x16x32_f16(awh[a], bxl[n], acc[a][n], 0, 0, 0);
            }
    }

    float bv[4][4];
#pragma unroll
    for (int a = 0; a < 4; ++a)
#pragma unroll
        for (int r = 0; r < 4; ++r) bv[a][r] = bias[co0 + wm * 64 + a * 16 + q * 4 + r];
#pragma unroll
    for (int a = 0; a < 4; ++a)
#pragma unroll
        for (int n = 0; n < 4; ++n) {
            const int l = l0 + wn * 64 + n * 16 + cl;
#pragma unroll
            for (int r = 0; r < 4; ++r) {
                const int co = co0 + wm * 64 + a * 16 + q * 4 + r;
                float vv = fmaxf(acc[a][n][r] * (1.f / 1048576.f) + bv[a][r], 0.f);
                out[((size_t)(b * C2V + co)) * L2V + l] = vv;
            }
        }
}

// ---------------- conv3 via f16 3-product MFMA: A=X windows (m=l), B=W (n=co) -------
__global__ __launch_bounds__(256, 2) void conv3_mfma_kernel(
    const float* __restrict__ in, const _Float16* __restrict__ WH,
    const _Float16* __restrict__ WL, const float* __restrict__ bias,
    _Float16* __restrict__ outh) {
    __shared__ _Float16 XsH[4 * 272], XsL[4 * 272];
    __shared__ _Float16 WsH[128 * 32], WsL[128 * 32];
    const int tid = threadIdx.x;
    const int wave = tid >> 6;
    const int lane = tid & 63;
    const int wm = wave >> 1, wn = wave & 1;
    const int q  = lane >> 4;
    const int cl = lane & 15;
    const int l0  = blockIdx.x * 128;
    const int co0 = blockIdx.y * 128;
    const int b   = blockIdx.z;
    const float* inb = in + (size_t)b * C2V * L2V;

    const int wrow  = lane >> 2;
    const int wseg  = lane & 3;
    const int wsoff = (wseg ^ ((wrow >> 1) & 3)) * 8;
    const int rq    = (q ^ ((cl >> 1) & 3)) * 8;

    floatx4 acc[4][4];
#pragma unroll
    for (int a = 0; a < 4; ++a)
#pragma unroll
        for (int n = 0; n < 4; ++n) acc[a][n] = (floatx4){0.f, 0.f, 0.f, 0.f};

    for (int ch = 0; ch < 64; ++ch) {
        __syncthreads();
        for (int n = tid; n < 4 * 264; n += 256) {
            int ci = n / 264;
            int m  = n - ci * 264;
            int p  = 2 * l0 - 4 + m;
            float v = (p >= 0 && p < L2V) ? inb[(size_t)(ch * 4 + ci) * L2V + p] * 1024.f : 0.f;
            _Float16 h = (_Float16)v;
            XsH[ci * 272 + m] = h;
            XsL[ci * 272 + m] = (_Float16)(v - (float)h);
        }
        const int k0 = ch * 32;
        for (int g = wave; g < 8; g += 4) {
            const _Float16* gh = WH + (size_t)(co0 + g * 16 + wrow) * 2048 + k0 + wsoff;
            const _Float16* gl = WL + (size_t)(co0 + g * 16 + wrow) * 2048 + k0 + wsoff;
            gload_lds16(gh, (char*)WsH + g * 1024);
            gload_lds16(gl, (char*)WsL + g * 1024);
        }
        asm volatile("s_waitcnt vmcnt(0)" ::: "memory");
        __syncthreads();

        half8 axh[4], axl[4], bwh[4], bwl[4];
#pragma unroll
        for (int a = 0; a < 4; ++a) {
            const int lrel = wm * 64 + a * 16 + cl;
            axh[a] = lds_read_half8_a4(&XsH[q * 272 + 2 * lrel]);
            axl[a] = lds_read_half8_a4(&XsL[q * 272 + 2 * lrel]);
        }
#pragma unroll
        for (int n = 0; n < 4; ++n) {
            const int ro = (wn * 64 + n * 16 + cl) * 32 + rq;
            bwh[n] = *(const half8*)&WsH[ro];
            bwl[n] = *(const half8*)&WsL[ro];
        }
#pragma unroll
        for (int a = 0; a < 4; ++a)
#pragma unroll
            for (int n = 0; n < 4; ++n) {
                acc[a][n] = __builtin_amdgcn_mfma_f32_16x16x32_f16(axh[a], bwh[n], acc[a][n], 0, 0, 0);
                acc[a][n] = __builtin_amdgcn_mfma_f32_16x16x32_f16(axl[a], bwh[n], acc[a][n], 0, 0, 0);
                acc[a][n] = __builtin_amdgcn_mfma_f32_16x16x32_f16(axh[a], bwl[n], acc[a][n], 0, 0, 0);
            }
    }

    float bv[4];
#pragma unroll
    for (int n = 0; n < 4; ++n) bv[n] = bias[co0 + wn * 64 + n * 16 + cl];
#pragma unroll
    for (int a = 0; a < 4; ++a)
#pragma unroll
        for (int n = 0; n < 4; ++n) {
            const int co = co0 + wn * 64 + n * 16 + cl;
#pragma unroll
            for (int r = 0; r < 4; ++r) {
                const int l = l0 + wm * 64 + a * 16 + q * 4 + r;
                float f = acc[a][n][r] * (1.f / 1048576.f) + bv[n];
                float s = f * 1024.f;
                _Float16 h = (_Float16)s;
                _Float16 lo = (_Float16)(s - (float)h);
                _Float16* dst = outh + ((size_t)b * L3V + l) * 1024 + co;
                dst[0] = h;
                dst[512] = lo;
            }
        }
}

// ---------------- fused codebook prep: rowsq*2^19 + x1024 hi/lo f16 split ----------
__global__ void cbprep_kernel(const float* __restrict__ cb, _Float16* __restrict__ y,
                              float* __restrict__ c2p) {
    const int r = blockIdx.x;
    const int lane = threadIdx.x;  // 64
    const float* row = cb + (size_t)r * 512;
    float4 a = *(const float4*)&row[lane * 8];
    float4 c = *(const float4*)&row[lane * 8 + 4];
    float s = a.x * a.x + a.y * a.y + a.z * a.z + a.w * a.w
            + c.x * c.x + c.y * c.y + c.z * c.z + c.w * c.w;
#pragma unroll
    for (int off = 32; off > 0; off >>= 1) s += __shfl_down(s, off, 64);
    if (lane == 0) c2p[r] = s * 524288.f;  // 2^19

    const float e[8] = {a.x, a.y, a.z, a.w, c.x, c.y, c.z, c.w};
    half8 hv, lv;
#pragma unroll
    for (int i = 0; i < 8; ++i) {
        float v = e[i] * 1024.f;
        _Float16 h = (_Float16)v;
        hv[i] = h;
        lv[i] = (_Float16)(v - (float)h);
    }
    *(half8*)(y + (size_t)r * 1024 + lane * 8) = hv;
    *(half8*)(y + (size_t)r * 1024 + 512 + lane * 8) = lv;
}

// ---------------- MFMA cross-GEMM + fused argmin, 128l x 256v block tile -----------
// Wave tile 64l x 128v (acc 4x8). Full V=2048 per block over 8 vt iterations.
// acc = Ahi*Bhi + Alo*Bhi + Ahi*Blo = 2^20*cross; key = acc - c2*2^19 (argmax).
// A/B tiles: linear LDS + XOR-swizzled global source segment + same XOR on read.
// DOUBLE-BUFFERED (T3 minimum 2-phase): stage tile t+1 into buf^1 right after the
// barrier, compute tile t from buf; MFMA cluster hides the load flight; one barrier
// per step, vmcnt(0) at loop top is ~free. 99 KB LDS -> 1 block/CU.
__global__ __launch_bounds__(256, 1) void cross_mfma_kernel(
    const _Float16* __restrict__ Af, const _Float16* __restrict__ Bf,
    const float* __restrict__ c2p,
    int* __restrict__ tok_i, float* __restrict__ tok_f) {

    __shared__ _Float16 AsH[2][128 * 32], AsL[2][128 * 32];   // 8 KB each plane
    __shared__ _Float16 BsH[2][256 * 32], BsL[2][256 * 32];   // 16 KB each plane
    __shared__ float slotv[2][128];
    __shared__ int   sloti[2][128];

    const int tid  = threadIdx.x;
    const int wave = tid >> 6;
    const int lane = tid & 63;
    const int wm = wave >> 1, wn = wave & 1;
    const int q  = lane >> 4;
    const int cl = lane & 15;

    const int l0 = blockIdx.x * 128;
    const int k  = blockIdx.y;
    const int b  = blockIdx.z;

    const _Float16* Ab = Af + (size_t)(b * L3V + l0) * 1024;
    const _Float16* Bb = Bf + (size_t)k * VOCABV * 1024;

    if (tid < 128) {
        slotv[0][tid] = -3.4e38f; slotv[1][tid] = -3.4e38f;
        sloti[0][tid] = 0;        sloti[1][tid] = 0;
    }

    const int rsub = tid >> 2;       // 0..63: row within 64-row staging group
    const int seg  = tid & 3;        // 16B segment within 64B row
    const int soff = (seg ^ ((rsub >> 1) & 3)) * 8;  // swizzled source offset (halfs)
    const int rq   = (q ^ ((cl >> 1) & 3)) * 8;      // swizzled read offset (halfs)

#define CROSS_STAGE(BUF, VT, KO) do { \
    const _Float16* Bt_ = Bb + (size_t)((VT) * 256) * 1024; \
    _Pragma("unroll") \
    for (int i_ = 0; i_ < 2; ++i_) { \
        const _Float16* ga_ = Ab + (size_t)(i_ * 64 + rsub) * 1024 + (KO) + soff; \
        gload_lds16(ga_,       (char*)&AsH[BUF][0] + i_ * 4096 + tid * 16); \
        gload_lds16(ga_ + 512, (char*)&AsL[BUF][0] + i_ * 4096 + tid * 16); \
    } \
    _Pragma("unroll") \
    for (int i_ = 0; i_ < 4; ++i_) { \
        const _Float16* gb_ = Bt_ + (size_t)(i_ * 64 + rsub) * 1024 + (KO) + soff; \
        gload_lds16(gb_,       (char*)&BsH[BUF][0] + i_ * 4096 + tid * 16); \
        gload_lds16(gb_ + 512, (char*)&BsL[BUF][0] + i_ * 4096 + tid * 16); \
    } \
} while (0)

    int cur = 0;
    CROSS_STAGE(0, 0, 0);

#pragma unroll 1
    for (int vt = 0; vt < 8; ++vt) {
        floatx4 acc[4][8];
#pragma unroll
        for (int mt = 0; mt < 4; ++mt)
#pragma unroll
            for (int nt = 0; nt < 8; ++nt) acc[mt][nt] = (floatx4){0.f, 0.f, 0.f, 0.f};

#pragma unroll 1
        for (int ko = 0; ko < 512; ko += 32) {
            asm volatile("s_waitcnt vmcnt(0)" ::: "memory");
            __syncthreads();           // buf[cur] staged + prev-tile reads complete

            // issue next-tile loads into buf[cur^1]; land under this tile's MFMA
            if (ko + 32 < 512)      CROSS_STAGE(cur ^ 1, vt, ko + 32);
            else if (vt + 1 < 8)    CROSS_STAGE(cur ^ 1, vt + 1, 0);
            __builtin_amdgcn_sched_barrier(0);

            half8 ah[4], al[4];
#pragma unroll
            for (int mt = 0; mt < 4; ++mt) {
                const int ro = (wm * 64 + mt * 16 + cl) * 32 + rq;
                ah[mt] = *(const half8*)&AsH[cur][ro];
                al[mt] = *(const half8*)&AsL[cur][ro];
            }
#pragma unroll
            for (int nt = 0; nt < 8; ++nt) {
                const int ro = (wn * 128 + nt * 16 + cl) * 32 + rq;
                half8 bh = *(const half8*)&BsH[cur][ro];
                half8 bl = *(const half8*)&BsL[cur][ro];
#pragma unroll
                for (int mt = 0; mt < 4; ++mt) {
                    acc[mt][nt] = __builtin_amdgcn_mfma_f32_16x16x32_f16(ah[mt], bh, acc[mt][nt], 0, 0, 0);
                    acc[mt][nt] = __builtin_amdgcn_mfma_f32_16x16x32_f16(al[mt], bh, acc[mt][nt], 0, 0, 0);
                    acc[mt][nt] = __builtin_amdgcn_mfma_f32_16x16x32_f16(ah[mt], bl, acc[mt][nt], 0, 0, 0);
                }
            }
            cur ^= 1;
        }

        // per-vt argmax epilogue
        float c2v[8];
#pragma unroll
        for (int nt = 0; nt < 8; ++nt)
            c2v[nt] = c2p[k * VOCABV + vt * 256 + wn * 128 + nt * 16 + cl];
#pragma unroll
        for (int mt = 0; mt < 4; ++mt)
#pragma unroll
            for (int r = 0; r < 4; ++r) {
                float bv = acc[mt][0][r] - c2v[0];
                int   bi = vt * 256 + wn * 128 + cl;
#pragma unroll
                for (int nt = 1; nt < 8; ++nt) {
                    float m = acc[mt][nt][r] - c2v[nt];
                    int   vi = vt * 256 + wn * 128 + nt * 16 + cl;
                    if (m > bv) { bv = m; bi = vi; }
                }
#pragma unroll
                for (int msk = 1; msk < 16; msk <<= 1) {
                    float ov = __shfl_xor(bv, msk, 64);
                    int   oi = __shfl_xor(bi, msk, 64);
                    if (ov > bv || (ov == bv && oi < bi)) { bv = ov; bi = oi; }
                }
                if (cl == 0) {
                    const int row = wm * 64 + mt * 16 + q * 4 + r;
                    float cur_v = slotv[wn][row];
                    int   ci  = sloti[wn][row];
                    if (bv > cur_v || (bv == cur_v && bi < ci)) {
                        slotv[wn][row] = bv;
                        sloti[wn][row] = bi;
                    }
                }
            }
    }
#undef CROSS_STAGE

    __syncthreads();
    if (tid < 128) {
        float v0 = slotv[0][tid], v1 = slotv[1][tid];
        int   i0 = sloti[0][tid], i1 = sloti[1][tid];
        bool t1 = (v1 > v0);  // wn=1 indices always larger: ties keep wn=0
        int best = t1 ? i1 : i0;
        const int n = (b * KCB + k) * L3V + l0 + tid;
        tok_i[n] = best;
        tok_f[n] = (float)best;
    }
}

// ---------------- embedding mean over 4 codebooks ----------------
__global__ void emb_kernel(const int* __restrict__ tokens, const float* __restrict__ E,
                           float* __restrict__ out) {
    const int l = blockIdx.x;
    const int b = blockIdx.y;
    const int h4 = threadIdx.x * 4;
    const int t0 = tokens[((size_t)(b * KCB + 0)) * L3V + l];
    const int t1 = tokens[((size_t)(b * KCB + 1)) * L3V + l];
    const int t2 = tokens[((size_t)(b * KCB + 2)) * L3V + l];
    const int t3 = tokens[((size_t)(b * KCB + 3)) * L3V + l];
    const float4 e0 = *(const float4*)&E[(size_t)t0 * 512 + h4];
    const float4 e1 = *(const float4*)&E[(size_t)t1 * 512 + h4];
    const float4 e2 = *(const float4*)&E[(size_t)t2 * 512 + h4];
    const float4 e3 = *(const float4*)&E[(size_t)t3 * 512 + h4];
    float4 r;
    r.x = (e0.x + e1.x + e2.x + e3.x) * 0.25f;
    r.y = (e0.y + e1.y + e2.y + e3.y) * 0.25f;
    r.z = (e0.z + e1.z + e2.z + e3.z) * 0.25f;
    r.w = (e0.w + e1.w + e2.w + e3.w) * 0.25f;
    *(float4*)&out[((size_t)b * L3V + l) * 512 + h4] = r;
}

extern "C" void kernel_launch(void* const* d_in, const int* in_sizes, int n_in,
                              void* d_out, int out_size, void* d_ws, size_t ws_size,
                              hipStream_t stream) {
    const float* audio = (const float*)d_in[0];
    const float* w1 = (const float*)d_in[1];
    const float* b1 = (const float*)d_in[2];
    const float* w2 = (const float*)d_in[3];
    const float* b2 = (const float*)d_in[4];
    const float* w3 = (const float*)d_in[5];
    const float* b3 = (const float*)d_in[6];
    const float* cb = (const float*)d_in[7];
    const float* E  = (const float*)d_in[8];

    float* out_tok = (float*)d_out;
    float* out_emb = out_tok + (size_t)B_ * KCB * L3V;

    float* ws = (float*)d_ws;
    size_t off = 0;
    float* x1  = ws + off; off += (size_t)B_ * C1V * L1V;            // conv1 out, later Afh
    float* x2f = ws + off; off += (size_t)B_ * C2V * L2V / 2;        // conv2 out
    float* bfh_f = ws + off; off += (size_t)KCB * VOCABV * 1024 / 2; // Bfh
    float* w2h_f = ws + off; off += (size_t)C2V * (C1V * 8) / 2;
    float* w2l_f = ws + off; off += (size_t)C2V * (C1V * 8) / 2;
    float* w3h_f = ws + off; off += (size_t)C3V * (C2V * 8) / 2;
    float* w3l_f = ws + off; off += (size_t)C3V * (C2V * 8) / 2;
    float* c2p = ws + off; off += (size_t)KCB * VOCABV;
    int*   tok = (int*)(ws + off); off += (size_t)B_ * KCB * L3V;

    _Float16* Afh = (_Float16*)x1;   // conv3 writes over x1 (dead after conv2)
    _Float16* Bfh = (_Float16*)bfh_f;
    _Float16* W2H = (_Float16*)w2h_f; _Float16* W2L = (_Float16*)w2l_f;
    _Float16* W3H = (_Float16*)w3h_f; _Float16* W3L = (_Float16*)w3l_f;

    wsplit_kernel<<<(C2V * C1V + 255) / 256, 256, 0, stream>>>(w2, W2H, W2L, C1V, C2V);
    wsplit_kernel<<<(C3V * C2V + 255) / 256, 256, 0, stream>>>(w3, W3H, W3L, C2V, C3V);

    conv1_kernel<<<dim3(L1V / 256, C1V, B_), 256, 0, stream>>>(audio, w1, b1, x1);

    conv2_mfma_kernel<<<dim3(L2V / 128, C2V / 128, B_), 256, 0, stream>>>(
        x1, W2H, W2L, b2, x2f);

    conv3_mfma_kernel<<<dim3(L3V / 128, C3V / 128, B_), 256, 0, stream>>>(
        x2f, W3H, W3L, b3, Afh);

    cbprep_kernel<<<KCB * VOCABV, 64, 0, stream>>>(cb, Bfh, c2p);

    cross_mfma_kernel<<<dim3(L3V / 128, KCB, B_), 256, 0, stream>>>(
        Afh, Bfh, c2p, tok, out_tok);

    emb_kernel<<<dim3(L3V, B_), 128, 0, stream>>>(tok, E, out_emb);
}

// Round 4
// 824.034 us; speedup vs baseline: 1.1522x; 1.1522x over previous
//
#include <hip/hip_runtime.h>
#include <hip/hip_bf16.h>
#include <stdint.h>

#define B_ 4
#define S_IN 32768
#define C1V 128
#define L1V 16384
#define C2V 256
#define L2V 8192
#define C3V 512
#define L3V 4096
#define VOCABV 2048
#define KCB 4

typedef _Float16 half8 __attribute__((ext_vector_type(8)));
typedef float floatx4 __attribute__((ext_vector_type(4)));

#define AS1 __attribute__((address_space(1)))
#define AS3 __attribute__((address_space(3)))

__device__ __forceinline__ void gload_lds16(const void* g, void* l) {
    __builtin_amdgcn_global_load_lds((const AS1 void*)g, (AS3 void*)l, 16, 0, 0);
}

// read 8 halfs at a 4B-aligned LDS address (4x ds_read_b32)
__device__ __forceinline__ half8 lds_read_half8_a4(const _Float16* p) {
    union { uint32_t u[4]; half8 h; } t;
    const uint32_t* w = (const uint32_t*)p;
    t.u[0] = w[0]; t.u[1] = w[1]; t.u[2] = w[2]; t.u[3] = w[3];
    return t.h;
}

// ---------------- conv1: [B,1,S] -> [B,128,16384], k=7 s=2 p=3, relu ----------------
__global__ void conv1_kernel(const float* __restrict__ x, const float* __restrict__ w,
                             const float* __restrict__ bias, float* __restrict__ out) {
    __shared__ float xs[2 * 256 + 6];
    __shared__ float ws[7];
    const int l0 = blockIdx.x * 256;
    const int co = blockIdx.y;
    const int b  = blockIdx.z;
    const int tid = threadIdx.x;
    const float* xb = x + (size_t)b * S_IN;
    for (int n = tid; n < 2 * 256 + 6; n += 256) {
        int p = 2 * l0 - 3 + n;
        xs[n] = (p >= 0 && p < S_IN) ? xb[p] : 0.f;
    }
    if (tid < 7) ws[tid] = w[co * 7 + tid];
    __syncthreads();
    float acc = bias[co];
    const int base = 2 * tid;
#pragma unroll
    for (int t = 0; t < 7; ++t) acc = fmaf(ws[t], xs[base + t], acc);
    acc = fmaxf(acc, 0.f);
    out[((size_t)(b * C1V + co)) * L1V + l0 + tid] = acc;
}

// ---------------- weight prep: w[co][ci][7] fp32 -> hi/lo f16 planes [co][ci*8+u] ----
__global__ void wsplit_kernel(const float* __restrict__ w, _Float16* __restrict__ wh,
                              _Float16* __restrict__ wl, int cin, int cout) {
    int idx = blockIdx.x * 256 + threadIdx.x;
    if (idx >= cin * cout) return;
    int co = idx / cin;
    int ci = idx - co * cin;
    const float* src = w + ((size_t)co * cin + ci) * 7;
    half8 h, l;
    h[0] = (_Float16)0.f; l[0] = (_Float16)0.f;
#pragma unroll
    for (int u = 1; u < 8; ++u) {
        float v = src[u - 1] * 1024.f;
        _Float16 hh = (_Float16)v;
        h[u] = hh;
        l[u] = (_Float16)(v - (float)hh);
    }
    size_t o = (size_t)co * (cin * 8) + ci * 8;
    *(half8*)(wh + o) = h;
    *(half8*)(wl + o) = l;
}

// Bank-conflict fix (rule 21): LDS dest stays linear (gload_lds writes base+lane*16);
// the 16B segment of the GLOBAL source is XOR-swizzled by row bits 1..2, and the
// fragment read applies the same XOR. Involution on both sides; row%16 carries the
// XOR bits so (cl>>1)&3 at read == (row>>1)&3 at write.

// ---------------- conv2 via f16 3-product MFMA: A=W (m=co), B=X windows (n=l) -------
__global__ __launch_bounds__(256, 2) void conv2_mfma_kernel(
    const float* __restrict__ in, const _Float16* __restrict__ WH,
    const _Float16* __restrict__ WL, const float* __restrict__ bias,
    float* __restrict__ out) {
    __shared__ _Float16 XsH[4 * 272], XsL[4 * 272];
    __shared__ _Float16 WsH[128 * 32], WsL[128 * 32];
    const int tid = threadIdx.x;
    const int wave = tid >> 6;
    const int lane = tid & 63;
    const int wm = wave >> 1, wn = wave & 1;
    const int q  = lane >> 4;
    const int cl = lane & 15;
    const int l0  = blockIdx.x * 128;
    const int co0 = blockIdx.y * 128;
    const int b   = blockIdx.z;
    const float* inb = in + (size_t)b * C1V * L1V;

    const int wrow  = lane >> 2;
    const int wseg  = lane & 3;
    const int wsoff = (wseg ^ ((wrow >> 1) & 3)) * 8;   // swizzled source offset (halfs)
    const int rq    = (q ^ ((cl >> 1) & 3)) * 8;        // swizzled read offset (halfs)

    floatx4 acc[4][4];
#pragma unroll
    for (int a = 0; a < 4; ++a)
#pragma unroll
        for (int n = 0; n < 4; ++n) acc[a][n] = (floatx4){0.f, 0.f, 0.f, 0.f};

    for (int ch = 0; ch < 32; ++ch) {
        __syncthreads();
        for (int n = tid; n < 4 * 264; n += 256) {
            int ci = n / 264;
            int m  = n - ci * 264;
            int p  = 2 * l0 - 4 + m;
            float v = (p >= 0 && p < L1V) ? inb[(size_t)(ch * 4 + ci) * L1V + p] * 1024.f : 0.f;
            _Float16 h = (_Float16)v;
            XsH[ci * 272 + m] = h;
            XsL[ci * 272 + m] = (_Float16)(v - (float)h);
        }
        const int k0 = ch * 32;
        for (int g = wave; g < 8; g += 4) {
            const _Float16* gh = WH + (size_t)(co0 + g * 16 + wrow) * 1024 + k0 + wsoff;
            const _Float16* gl = WL + (size_t)(co0 + g * 16 + wrow) * 1024 + k0 + wsoff;
            gload_lds16(gh, (char*)WsH + g * 1024);
            gload_lds16(gl, (char*)WsL + g * 1024);
        }
        asm volatile("s_waitcnt vmcnt(0)" ::: "memory");
        __syncthreads();

        half8 awh[4], awl[4], bxh[4], bxl[4];
#pragma unroll
        for (int a = 0; a < 4; ++a) {
            const int ro = (wm * 64 + a * 16 + cl) * 32 + rq;
            awh[a] = *(const half8*)&WsH[ro];
            awl[a] = *(const half8*)&WsL[ro];
        }
#pragma unroll
        for (int n = 0; n < 4; ++n) {
            const int lrel = wn * 64 + n * 16 + cl;
            bxh[n] = lds_read_half8_a4(&XsH[q * 272 + 2 * lrel]);
            bxl[n] = lds_read_half8_a4(&XsL[q * 272 + 2 * lrel]);
        }
#pragma unroll
        for (int a = 0; a < 4; ++a)
#pragma unroll
            for (int n = 0; n < 4; ++n) {
                acc[a][n] = __builtin_amdgcn_mfma_f32_16x16x32_f16(awh[a], bxh[n], acc[a][n], 0, 0, 0);
                acc[a][n] = __builtin_amdgcn_mfma_f32_16x16x32_f16(awl[a], bxh[n], acc[a][n], 0, 0, 0);
                acc[a][n] = __builtin_amdgcn_mfma_f32_16x16x32_f16(awh[a], bxl[n], acc[a][n], 0, 0, 0);
            }
    }

    float bv[4][4];
#pragma unroll
    for (int a = 0; a < 4; ++a)
#pragma unroll
        for (int r = 0; r < 4; ++r) bv[a][r] = bias[co0 + wm * 64 + a * 16 + q * 4 + r];
#pragma unroll
    for (int a = 0; a < 4; ++a)
#pragma unroll
        for (int n = 0; n < 4; ++n) {
            const int l = l0 + wn * 64 + n * 16 + cl;
#pragma unroll
            for (int r = 0; r < 4; ++r) {
                const int co = co0 + wm * 64 + a * 16 + q * 4 + r;
                float vv = fmaxf(acc[a][n][r] * (1.f / 1048576.f) + bv[a][r], 0.f);
                out[((size_t)(b * C2V + co)) * L2V + l] = vv;
            }
        }
}

// ---------------- conv3 via f16 3-product MFMA: A=X windows (m=l), B=W (n=co) -------
__global__ __launch_bounds__(256, 2) void conv3_mfma_kernel(
    const float* __restrict__ in, const _Float16* __restrict__ WH,
    const _Float16* __restrict__ WL, const float* __restrict__ bias,
    _Float16* __restrict__ outh) {
    __shared__ _Float16 XsH[4 * 272], XsL[4 * 272];
    __shared__ _Float16 WsH[128 * 32], WsL[128 * 32];
    const int tid = threadIdx.x;
    const int wave = tid >> 6;
    const int lane = tid & 63;
    const int wm = wave >> 1, wn = wave & 1;
    const int q  = lane >> 4;
    const int cl = lane & 15;
    const int l0  = blockIdx.x * 128;
    const int co0 = blockIdx.y * 128;
    const int b   = blockIdx.z;
    const float* inb = in + (size_t)b * C2V * L2V;

    const int wrow  = lane >> 2;
    const int wseg  = lane & 3;
    const int wsoff = (wseg ^ ((wrow >> 1) & 3)) * 8;
    const int rq    = (q ^ ((cl >> 1) & 3)) * 8;

    floatx4 acc[4][4];
#pragma unroll
    for (int a = 0; a < 4; ++a)
#pragma unroll
        for (int n = 0; n < 4; ++n) acc[a][n] = (floatx4){0.f, 0.f, 0.f, 0.f};

    for (int ch = 0; ch < 64; ++ch) {
        __syncthreads();
        for (int n = tid; n < 4 * 264; n += 256) {
            int ci = n / 264;
            int m  = n - ci * 264;
            int p  = 2 * l0 - 4 + m;
            float v = (p >= 0 && p < L2V) ? inb[(size_t)(ch * 4 + ci) * L2V + p] * 1024.f : 0.f;
            _Float16 h = (_Float16)v;
            XsH[ci * 272 + m] = h;
            XsL[ci * 272 + m] = (_Float16)(v - (float)h);
        }
        const int k0 = ch * 32;
        for (int g = wave; g < 8; g += 4) {
            const _Float16* gh = WH + (size_t)(co0 + g * 16 + wrow) * 2048 + k0 + wsoff;
            const _Float16* gl = WL + (size_t)(co0 + g * 16 + wrow) * 2048 + k0 + wsoff;
            gload_lds16(gh, (char*)WsH + g * 1024);
            gload_lds16(gl, (char*)WsL + g * 1024);
        }
        asm volatile("s_waitcnt vmcnt(0)" ::: "memory");
        __syncthreads();

        half8 axh[4], axl[4], bwh[4], bwl[4];
#pragma unroll
        for (int a = 0; a < 4; ++a) {
            const int lrel = wm * 64 + a * 16 + cl;
            axh[a] = lds_read_half8_a4(&XsH[q * 272 + 2 * lrel]);
            axl[a] = lds_read_half8_a4(&XsL[q * 272 + 2 * lrel]);
        }
#pragma unroll
        for (int n = 0; n < 4; ++n) {
            const int ro = (wn * 64 + n * 16 + cl) * 32 + rq;
            bwh[n] = *(const half8*)&WsH[ro];
            bwl[n] = *(const half8*)&WsL[ro];
        }
#pragma unroll
        for (int a = 0; a < 4; ++a)
#pragma unroll
            for (int n = 0; n < 4; ++n) {
                acc[a][n] = __builtin_amdgcn_mfma_f32_16x16x32_f16(axh[a], bwh[n], acc[a][n], 0, 0, 0);
                acc[a][n] = __builtin_amdgcn_mfma_f32_16x16x32_f16(axl[a], bwh[n], acc[a][n], 0, 0, 0);
                acc[a][n] = __builtin_amdgcn_mfma_f32_16x16x32_f16(axh[a], bwl[n], acc[a][n], 0, 0, 0);
            }
    }

    float bv[4];
#pragma unroll
    for (int n = 0; n < 4; ++n) bv[n] = bias[co0 + wn * 64 + n * 16 + cl];
#pragma unroll
    for (int a = 0; a < 4; ++a)
#pragma unroll
        for (int n = 0; n < 4; ++n) {
            const int co = co0 + wn * 64 + n * 16 + cl;
#pragma unroll
            for (int r = 0; r < 4; ++r) {
                const int l = l0 + wm * 64 + a * 16 + q * 4 + r;
                float f = acc[a][n][r] * (1.f / 1048576.f) + bv[n];
                float s = f * 1024.f;
                _Float16 h = (_Float16)s;
                _Float16 lo = (_Float16)(s - (float)h);
                _Float16* dst = outh + ((size_t)b * L3V + l) * 1024 + co;
                dst[0] = h;
                dst[512] = lo;
            }
        }
}

// ---------------- fused codebook prep: rowsq*2^19 + x1024 hi/lo f16 split ----------
__global__ void cbprep_kernel(const float* __restrict__ cb, _Float16* __restrict__ y,
                              float* __restrict__ c2p) {
    const int r = blockIdx.x;
    const int lane = threadIdx.x;  // 64
    const float* row = cb + (size_t)r * 512;
    float4 a = *(const float4*)&row[lane * 8];
    float4 c = *(const float4*)&row[lane * 8 + 4];
    float s = a.x * a.x + a.y * a.y + a.z * a.z + a.w * a.w
            + c.x * c.x + c.y * c.y + c.z * c.z + c.w * c.w;
#pragma unroll
    for (int off = 32; off > 0; off >>= 1) s += __shfl_down(s, off, 64);
    if (lane == 0) c2p[r] = s * 524288.f;  // 2^19

    const float e[8] = {a.x, a.y, a.z, a.w, c.x, c.y, c.z, c.w};
    half8 hv, lv;
#pragma unroll
    for (int i = 0; i < 8; ++i) {
        float v = e[i] * 1024.f;
        _Float16 h = (_Float16)v;
        hv[i] = h;
        lv[i] = (_Float16)(v - (float)h);
    }
    *(half8*)(y + (size_t)r * 1024 + lane * 8) = hv;
    *(half8*)(y + (size_t)r * 1024 + 512 + lane * 8) = lv;
}

// ---------------- MFMA cross-GEMM + fused argmin, 128l x 256v block tile -----------
// Wave tile 64l x 128v (acc 4x8). Full V=2048 per block over 8 vt iterations.
// acc = Ahi*Bhi + Alo*Bhi + Ahi*Blo = 2^20*cross; key = acc - c2*2^19 (argmax).
// A: DIRECT global->VGPR loads (each fragment is a contiguous 16B of Af; L2 provides
//    the 2x intra-block reuse LDS used to give). Issued before the B-stage so the
//    compiler waits on them with counted vmcnt, not vmcnt(0).
// B: LDS double-buffered (2 x 32 KB -> 65 KB total, 2 blocks/CU preserved), linear
//    dest + XOR-swizzled global source + same XOR on read. Stage t+1 issued right
//    after the barrier; MFMA cluster hides the flight; one barrier per step.
__global__ __launch_bounds__(256, 2) void cross_mfma_kernel(
    const _Float16* __restrict__ Af, const _Float16* __restrict__ Bf,
    const float* __restrict__ c2p,
    int* __restrict__ tok_i, float* __restrict__ tok_f) {

    __shared__ _Float16 BsH[2][256 * 32], BsL[2][256 * 32];   // 16 KB per plane per buf
    __shared__ float slotv[2][128];
    __shared__ int   sloti[2][128];

    const int tid  = threadIdx.x;
    const int wave = tid >> 6;
    const int lane = tid & 63;
    const int wm = wave >> 1, wn = wave & 1;
    const int q  = lane >> 4;
    const int cl = lane & 15;

    const int l0 = blockIdx.x * 128;
    const int k  = blockIdx.y;
    const int b  = blockIdx.z;

    const _Float16* Ab = Af + (size_t)(b * L3V + l0) * 1024;
    const _Float16* Bb = Bf + (size_t)k * VOCABV * 1024;

    if (tid < 128) {
        slotv[0][tid] = -3.4e38f; slotv[1][tid] = -3.4e38f;
        sloti[0][tid] = 0;        sloti[1][tid] = 0;
    }

    const int rsub = tid >> 2;       // 0..63: row within 64-row staging group
    const int seg  = tid & 3;        // 16B segment within 64B row
    const int soff = (seg ^ ((rsub >> 1) & 3)) * 8;  // swizzled source offset (halfs)
    const int rq   = (q ^ ((cl >> 1) & 3)) * 8;      // swizzled read offset (halfs)

    // per-lane A fragment base: row = wm*64 + cl (mt adds 16 rows), col base q*8
    const _Float16* Arow = Ab + (size_t)(wm * 64 + cl) * 1024 + q * 8;

#define B_STAGE(BUF, VT, KO) do { \
    const _Float16* Bt_ = Bb + (size_t)((VT) * 256) * 1024; \
    _Pragma("unroll") \
    for (int i_ = 0; i_ < 4; ++i_) { \
        const _Float16* gb_ = Bt_ + (size_t)(i_ * 64 + rsub) * 1024 + (KO) + soff; \
        gload_lds16(gb_,       (char*)&BsH[BUF][0] + i_ * 4096 + tid * 16); \
        gload_lds16(gb_ + 512, (char*)&BsL[BUF][0] + i_ * 4096 + tid * 16); \
    } \
} while (0)

    int cur = 0;
    B_STAGE(0, 0, 0);

#pragma unroll 1
    for (int vt = 0; vt < 8; ++vt) {
        floatx4 acc[4][8];
#pragma unroll
        for (int mt = 0; mt < 4; ++mt)
#pragma unroll
            for (int nt = 0; nt < 8; ++nt) acc[mt][nt] = (floatx4){0.f, 0.f, 0.f, 0.f};

#pragma unroll 1
        for (int ko = 0; ko < 512; ko += 32) {
            asm volatile("s_waitcnt vmcnt(0)" ::: "memory");
            __syncthreads();           // buf[cur] staged + prev reads complete

            // A fragments: direct global loads (issued FIRST -> counted wait later)
            half8 ah[4], al[4];
#pragma unroll
            for (int mt = 0; mt < 4; ++mt) {
                const _Float16* pa = Arow + (size_t)(mt * 16) * 1024 + ko;
                ah[mt] = *(const half8*)pa;
                al[mt] = *(const half8*)(pa + 512);
            }

            // issue next B tile into the other buffer; lands under this MFMA cluster
            if (ko + 32 < 512)      B_STAGE(cur ^ 1, vt, ko + 32);
            else if (vt + 1 < 8)    B_STAGE(cur ^ 1, vt + 1, 0);
            __builtin_amdgcn_sched_barrier(0);

#pragma unroll
            for (int nt = 0; nt < 8; ++nt) {
                const int ro = (wn * 128 + nt * 16 + cl) * 32 + rq;
                half8 bh = *(const half8*)&BsH[cur][ro];
                half8 bl = *(const half8*)&BsL[cur][ro];
#pragma unroll
                for (int mt = 0; mt < 4; ++mt) {
                    acc[mt][nt] = __builtin_amdgcn_mfma_f32_16x16x32_f16(ah[mt], bh, acc[mt][nt], 0, 0, 0);
                    acc[mt][nt] = __builtin_amdgcn_mfma_f32_16x16x32_f16(al[mt], bh, acc[mt][nt], 0, 0, 0);
                    acc[mt][nt] = __builtin_amdgcn_mfma_f32_16x16x32_f16(ah[mt], bl, acc[mt][nt], 0, 0, 0);
                }
            }
            cur ^= 1;
        }

        // per-vt argmax epilogue
        float c2v[8];
#pragma unroll
        for (int nt = 0; nt < 8; ++nt)
            c2v[nt] = c2p[k * VOCABV + vt * 256 + wn * 128 + nt * 16 + cl];
#pragma unroll
        for (int mt = 0; mt < 4; ++mt)
#pragma unroll
            for (int r = 0; r < 4; ++r) {
                float bv = acc[mt][0][r] - c2v[0];
                int   bi = vt * 256 + wn * 128 + cl;
#pragma unroll
                for (int nt = 1; nt < 8; ++nt) {
                    float m = acc[mt][nt][r] - c2v[nt];
                    int   vi = vt * 256 + wn * 128 + nt * 16 + cl;
                    if (m > bv) { bv = m; bi = vi; }
                }
#pragma unroll
                for (int msk = 1; msk < 16; msk <<= 1) {
                    float ov = __shfl_xor(bv, msk, 64);
                    int   oi = __shfl_xor(bi, msk, 64);
                    if (ov > bv || (ov == bv && oi < bi)) { bv = ov; bi = oi; }
                }
                if (cl == 0) {
                    const int row = wm * 64 + mt * 16 + q * 4 + r;
                    float cur_v = slotv[wn][row];
                    int   ci  = sloti[wn][row];
                    if (bv > cur_v || (bv == cur_v && bi < ci)) {
                        slotv[wn][row] = bv;
                        sloti[wn][row] = bi;
                    }
                }
            }
    }
#undef B_STAGE

    __syncthreads();
    if (tid < 128) {
        float v0 = slotv[0][tid], v1 = slotv[1][tid];
        int   i0 = sloti[0][tid], i1 = sloti[1][tid];
        bool t1 = (v1 > v0);  // wn=1 indices always larger: ties keep wn=0
        int best = t1 ? i1 : i0;
        const int n = (b * KCB + k) * L3V + l0 + tid;
        tok_i[n] = best;
        tok_f[n] = (float)best;
    }
}

// ---------------- embedding mean over 4 codebooks ----------------
__global__ void emb_kernel(const int* __restrict__ tokens, const float* __restrict__ E,
                           float* __restrict__ out) {
    const int l = blockIdx.x;
    const int b = blockIdx.y;
    const int h4 = threadIdx.x * 4;
    const int t0 = tokens[((size_t)(b * KCB + 0)) * L3V + l];
    const int t1 = tokens[((size_t)(b * KCB + 1)) * L3V + l];
    const int t2 = tokens[((size_t)(b * KCB + 2)) * L3V + l];
    const int t3 = tokens[((size_t)(b * KCB + 3)) * L3V + l];
    const float4 e0 = *(const float4*)&E[(size_t)t0 * 512 + h4];
    const float4 e1 = *(const float4*)&E[(size_t)t1 * 512 + h4];
    const float4 e2 = *(const float4*)&E[(size_t)t2 * 512 + h4];
    const float4 e3 = *(const float4*)&E[(size_t)t3 * 512 + h4];
    float4 r;
    r.x = (e0.x + e1.x + e2.x + e3.x) * 0.25f;
    r.y = (e0.y + e1.y + e2.y + e3.y) * 0.25f;
    r.z = (e0.z + e1.z + e2.z + e3.z) * 0.25f;
    r.w = (e0.w + e1.w + e2.w + e3.w) * 0.25f;
    *(float4*)&out[((size_t)b * L3V + l) * 512 + h4] = r;
}

extern "C" void kernel_launch(void* const* d_in, const int* in_sizes, int n_in,
                              void* d_out, int out_size, void* d_ws, size_t ws_size,
                              hipStream_t stream) {
    const float* audio = (const float*)d_in[0];
    const float* w1 = (const float*)d_in[1];
    const float* b1 = (const float*)d_in[2];
    const float* w2 = (const float*)d_in[3];
    const float* b2 = (const float*)d_in[4];
    const float* w3 = (const float*)d_in[5];
    const float* b3 = (const float*)d_in[6];
    const float* cb = (const float*)d_in[7];
    const float* E  = (const float*)d_in[8];

    float* out_tok = (float*)d_out;
    float* out_emb = out_tok + (size_t)B_ * KCB * L3V;

    float* ws = (float*)d_ws;
    size_t off = 0;
    float* x1  = ws + off; off += (size_t)B_ * C1V * L1V;            // conv1 out, later Afh
    float* x2f = ws + off; off += (size_t)B_ * C2V * L2V / 2;        // conv2 out
    float* bfh_f = ws + off; off += (size_t)KCB * VOCABV * 1024 / 2; // Bfh
    float* w2h_f = ws + off; off += (size_t)C2V * (C1V * 8) / 2;
    float* w2l_f = ws + off; off += (size_t)C2V * (C1V * 8) / 2;
    float* w3h_f = ws + off; off += (size_t)C3V * (C2V * 8) / 2;
    float* w3l_f = ws + off; off += (size_t)C3V * (C2V * 8) / 2;
    float* c2p = ws + off; off += (size_t)KCB * VOCABV;
    int*   tok = (int*)(ws + off); off += (size_t)B_ * KCB * L3V;

    _Float16* Afh = (_Float16*)x1;   // conv3 writes over x1 (dead after conv2)
    _Float16* Bfh = (_Float16*)bfh_f;
    _Float16* W2H = (_Float16*)w2h_f; _Float16* W2L = (_Float16*)w2l_f;
    _Float16* W3H = (_Float16*)w3h_f; _Float16* W3L = (_Float16*)w3l_f;

    wsplit_kernel<<<(C2V * C1V + 255) / 256, 256, 0, stream>>>(w2, W2H, W2L, C1V, C2V);
    wsplit_kernel<<<(C3V * C2V + 255) / 256, 256, 0, stream>>>(w3, W3H, W3L, C2V, C3V);

    conv1_kernel<<<dim3(L1V / 256, C1V, B_), 256, 0, stream>>>(audio, w1, b1, x1);

    conv2_mfma_kernel<<<dim3(L2V / 128, C2V / 128, B_), 256, 0, stream>>>(
        x1, W2H, W2L, b2, x2f);

    conv3_mfma_kernel<<<dim3(L3V / 128, C3V / 128, B_), 256, 0, stream>>>(
        x2f, W3H, W3L, b3, Afh);

    cbprep_kernel<<<KCB * VOCABV, 64, 0, stream>>>(cb, Bfh, c2p);

    cross_mfma_kernel<<<dim3(L3V / 128, KCB, B_), 256, 0, stream>>>(
        Afh, Bfh, c2p, tok, out_tok);

    emb_kernel<<<dim3(L3V, B_), 128, 0, stream>>>(tok, E, out_emb);
}

// Round 5
// 784.809 us; speedup vs baseline: 1.2098x; 1.0500x over previous
//
#include <hip/hip_runtime.h>
#include <hip/hip_bf16.h>
#include <stdint.h>

#define B_ 4
#define S_IN 32768
#define C1V 128
#define L1V 16384
#define C2V 256
#define L2V 8192
#define C3V 512
#define L3V 4096
#define VOCABV 2048
#define KCB 4

typedef _Float16 half8 __attribute__((ext_vector_type(8)));
typedef float floatx4 __attribute__((ext_vector_type(4)));

#define AS1 __attribute__((address_space(1)))
#define AS3 __attribute__((address_space(3)))

__device__ __forceinline__ void gload_lds16(const void* g, void* l) {
    __builtin_amdgcn_global_load_lds((const AS1 void*)g, (AS3 void*)l, 16, 0, 0);
}

// read 8 halfs at a 4B-aligned LDS address (4x ds_read_b32)
__device__ __forceinline__ half8 lds_read_half8_a4(const _Float16* p) {
    union { uint32_t u[4]; half8 h; } t;
    const uint32_t* w = (const uint32_t*)p;
    t.u[0] = w[0]; t.u[1] = w[1]; t.u[2] = w[2]; t.u[3] = w[3];
    return t.h;
}

// ---------------- conv1: [B,1,S] -> [B,128,16384], k=7 s=2 p=3, relu ----------------
__global__ void conv1_kernel(const float* __restrict__ x, const float* __restrict__ w,
                             const float* __restrict__ bias, float* __restrict__ out) {
    __shared__ float xs[2 * 256 + 6];
    __shared__ float ws[7];
    const int l0 = blockIdx.x * 256;
    const int co = blockIdx.y;
    const int b  = blockIdx.z;
    const int tid = threadIdx.x;
    const float* xb = x + (size_t)b * S_IN;
    for (int n = tid; n < 2 * 256 + 6; n += 256) {
        int p = 2 * l0 - 3 + n;
        xs[n] = (p >= 0 && p < S_IN) ? xb[p] : 0.f;
    }
    if (tid < 7) ws[tid] = w[co * 7 + tid];
    __syncthreads();
    float acc = bias[co];
    const int base = 2 * tid;
#pragma unroll
    for (int t = 0; t < 7; ++t) acc = fmaf(ws[t], xs[base + t], acc);
    acc = fmaxf(acc, 0.f);
    out[((size_t)(b * C1V + co)) * L1V + l0 + tid] = acc;
}

// ---------------- weight prep: w[co][ci][7] fp32 -> hi/lo f16 planes [co][ci*8+u] ----
__global__ void wsplit_kernel(const float* __restrict__ w, _Float16* __restrict__ wh,
                              _Float16* __restrict__ wl, int cin, int cout) {
    int idx = blockIdx.x * 256 + threadIdx.x;
    if (idx >= cin * cout) return;
    int co = idx / cin;
    int ci = idx - co * cin;
    const float* src = w + ((size_t)co * cin + ci) * 7;
    half8 h, l;
    h[0] = (_Float16)0.f; l[0] = (_Float16)0.f;
#pragma unroll
    for (int u = 1; u < 8; ++u) {
        float v = src[u - 1] * 1024.f;
        _Float16 hh = (_Float16)v;
        h[u] = hh;
        l[u] = (_Float16)(v - (float)hh);
    }
    size_t o = (size_t)co * (cin * 8) + ci * 8;
    *(half8*)(wh + o) = h;
    *(half8*)(wl + o) = l;
}

// Bank-conflict fix (rule 21): LDS dest stays linear (gload_lds writes base+lane*16);
// the 16B segment of the GLOBAL source is XOR-swizzled by row bits 1..2, and the
// fragment read applies the same XOR. Involution on both sides; row%16 carries the
// XOR bits so (cl>>1)&3 at read == (row>>1)&3 at write.

// ---------------- conv2 via f16 3-product MFMA: A=W (m=co), B=X windows (n=l) -------
__global__ __launch_bounds__(256, 2) void conv2_mfma_kernel(
    const float* __restrict__ in, const _Float16* __restrict__ WH,
    const _Float16* __restrict__ WL, const float* __restrict__ bias,
    float* __restrict__ out) {
    __shared__ _Float16 XsH[4 * 272], XsL[4 * 272];
    __shared__ _Float16 WsH[128 * 32], WsL[128 * 32];
    const int tid = threadIdx.x;
    const int wave = tid >> 6;
    const int lane = tid & 63;
    const int wm = wave >> 1, wn = wave & 1;
    const int q  = lane >> 4;
    const int cl = lane & 15;
    const int l0  = blockIdx.x * 128;
    const int co0 = blockIdx.y * 128;
    const int b   = blockIdx.z;
    const float* inb = in + (size_t)b * C1V * L1V;

    const int wrow  = lane >> 2;
    const int wseg  = lane & 3;
    const int wsoff = (wseg ^ ((wrow >> 1) & 3)) * 8;   // swizzled source offset (halfs)
    const int rq    = (q ^ ((cl >> 1) & 3)) * 8;        // swizzled read offset (halfs)

    floatx4 acc[4][4];
#pragma unroll
    for (int a = 0; a < 4; ++a)
#pragma unroll
        for (int n = 0; n < 4; ++n) acc[a][n] = (floatx4){0.f, 0.f, 0.f, 0.f};

    for (int ch = 0; ch < 32; ++ch) {
        __syncthreads();
        for (int n = tid; n < 4 * 264; n += 256) {
            int ci = n / 264;
            int m  = n - ci * 264;
            int p  = 2 * l0 - 4 + m;
            float v = (p >= 0 && p < L1V) ? inb[(size_t)(ch * 4 + ci) * L1V + p] * 1024.f : 0.f;
            _Float16 h = (_Float16)v;
            XsH[ci * 272 + m] = h;
            XsL[ci * 272 + m] = (_Float16)(v - (float)h);
        }
        const int k0 = ch * 32;
        for (int g = wave; g < 8; g += 4) {
            const _Float16* gh = WH + (size_t)(co0 + g * 16 + wrow) * 1024 + k0 + wsoff;
            const _Float16* gl = WL + (size_t)(co0 + g * 16 + wrow) * 1024 + k0 + wsoff;
            gload_lds16(gh, (char*)WsH + g * 1024);
            gload_lds16(gl, (char*)WsL + g * 1024);
        }
        asm volatile("s_waitcnt vmcnt(0)" ::: "memory");
        __syncthreads();

        half8 awh[4], awl[4], bxh[4], bxl[4];
#pragma unroll
        for (int a = 0; a < 4; ++a) {
            const int ro = (wm * 64 + a * 16 + cl) * 32 + rq;
            awh[a] = *(const half8*)&WsH[ro];
            awl[a] = *(const half8*)&WsL[ro];
        }
#pragma unroll
        for (int n = 0; n < 4; ++n) {
            const int lrel = wn * 64 + n * 16 + cl;
            bxh[n] = lds_read_half8_a4(&XsH[q * 272 + 2 * lrel]);
            bxl[n] = lds_read_half8_a4(&XsL[q * 272 + 2 * lrel]);
        }
#pragma unroll
        for (int a = 0; a < 4; ++a)
#pragma unroll
            for (int n = 0; n < 4; ++n) {
                acc[a][n] = __builtin_amdgcn_mfma_f32_16x16x32_f16(awh[a], bxh[n], acc[a][n], 0, 0, 0);
                acc[a][n] = __builtin_amdgcn_mfma_f32_16x16x32_f16(awl[a], bxh[n], acc[a][n], 0, 0, 0);
                acc[a][n] = __builtin_amdgcn_mfma_f32_16x16x32_f16(awh[a], bxl[n], acc[a][n], 0, 0, 0);
            }
    }

    float bv[4][4];
#pragma unroll
    for (int a = 0; a < 4; ++a)
#pragma unroll
        for (int r = 0; r < 4; ++r) bv[a][r] = bias[co0 + wm * 64 + a * 16 + q * 4 + r];
#pragma unroll
    for (int a = 0; a < 4; ++a)
#pragma unroll
        for (int n = 0; n < 4; ++n) {
            const int l = l0 + wn * 64 + n * 16 + cl;
#pragma unroll
            for (int r = 0; r < 4; ++r) {
                const int co = co0 + wm * 64 + a * 16 + q * 4 + r;
                float vv = fmaxf(acc[a][n][r] * (1.f / 1048576.f) + bv[a][r], 0.f);
                out[((size_t)(b * C2V + co)) * L2V + l] = vv;
            }
        }
}

// ---------------- conv3 via f16 3-product MFMA: A=X windows (m=l), B=W (n=co) -------
__global__ __launch_bounds__(256, 2) void conv3_mfma_kernel(
    const float* __restrict__ in, const _Float16* __restrict__ WH,
    const _Float16* __restrict__ WL, const float* __restrict__ bias,
    _Float16* __restrict__ outh) {
    __shared__ _Float16 XsH[4 * 272], XsL[4 * 272];
    __shared__ _Float16 WsH[128 * 32], WsL[128 * 32];
    const int tid = threadIdx.x;
    const int wave = tid >> 6;
    const int lane = tid & 63;
    const int wm = wave >> 1, wn = wave & 1;
    const int q  = lane >> 4;
    const int cl = lane & 15;
    const int l0  = blockIdx.x * 128;
    const int co0 = blockIdx.y * 128;
    const int b   = blockIdx.z;
    const float* inb = in + (size_t)b * C2V * L2V;

    const int wrow  = lane >> 2;
    const int wseg  = lane & 3;
    const int wsoff = (wseg ^ ((wrow >> 1) & 3)) * 8;
    const int rq    = (q ^ ((cl >> 1) & 3)) * 8;

    floatx4 acc[4][4];
#pragma unroll
    for (int a = 0; a < 4; ++a)
#pragma unroll
        for (int n = 0; n < 4; ++n) acc[a][n] = (floatx4){0.f, 0.f, 0.f, 0.f};

    for (int ch = 0; ch < 64; ++ch) {
        __syncthreads();
        for (int n = tid; n < 4 * 264; n += 256) {
            int ci = n / 264;
            int m  = n - ci * 264;
            int p  = 2 * l0 - 4 + m;
            float v = (p >= 0 && p < L2V) ? inb[(size_t)(ch * 4 + ci) * L2V + p] * 1024.f : 0.f;
            _Float16 h = (_Float16)v;
            XsH[ci * 272 + m] = h;
            XsL[ci * 272 + m] = (_Float16)(v - (float)h);
        }
        const int k0 = ch * 32;
        for (int g = wave; g < 8; g += 4) {
            const _Float16* gh = WH + (size_t)(co0 + g * 16 + wrow) * 2048 + k0 + wsoff;
            const _Float16* gl = WL + (size_t)(co0 + g * 16 + wrow) * 2048 + k0 + wsoff;
            gload_lds16(gh, (char*)WsH + g * 1024);
            gload_lds16(gl, (char*)WsL + g * 1024);
        }
        asm volatile("s_waitcnt vmcnt(0)" ::: "memory");
        __syncthreads();

        half8 axh[4], axl[4], bwh[4], bwl[4];
#pragma unroll
        for (int a = 0; a < 4; ++a) {
            const int lrel = wm * 64 + a * 16 + cl;
            axh[a] = lds_read_half8_a4(&XsH[q * 272 + 2 * lrel]);
            axl[a] = lds_read_half8_a4(&XsL[q * 272 + 2 * lrel]);
        }
#pragma unroll
        for (int n = 0; n < 4; ++n) {
            const int ro = (wn * 64 + n * 16 + cl) * 32 + rq;
            bwh[n] = *(const half8*)&WsH[ro];
            bwl[n] = *(const half8*)&WsL[ro];
        }
#pragma unroll
        for (int a = 0; a < 4; ++a)
#pragma unroll
            for (int n = 0; n < 4; ++n) {
                acc[a][n] = __builtin_amdgcn_mfma_f32_16x16x32_f16(axh[a], bwh[n], acc[a][n], 0, 0, 0);
                acc[a][n] = __builtin_amdgcn_mfma_f32_16x16x32_f16(axl[a], bwh[n], acc[a][n], 0, 0, 0);
                acc[a][n] = __builtin_amdgcn_mfma_f32_16x16x32_f16(axh[a], bwl[n], acc[a][n], 0, 0, 0);
            }
    }

    float bv[4];
#pragma unroll
    for (int n = 0; n < 4; ++n) bv[n] = bias[co0 + wn * 64 + n * 16 + cl];
#pragma unroll
    for (int a = 0; a < 4; ++a)
#pragma unroll
        for (int n = 0; n < 4; ++n) {
            const int co = co0 + wn * 64 + n * 16 + cl;
#pragma unroll
            for (int r = 0; r < 4; ++r) {
                const int l = l0 + wm * 64 + a * 16 + q * 4 + r;
                float f = acc[a][n][r] * (1.f / 1048576.f) + bv[n];
                float s = f * 1024.f;
                _Float16 h = (_Float16)s;
                _Float16 lo = (_Float16)(s - (float)h);
                _Float16* dst = outh + ((size_t)b * L3V + l) * 1024 + co;
                dst[0] = h;
                dst[512] = lo;
            }
        }
}

// ---------------- fused codebook prep: rowsq*2^19 + x1024 hi/lo f16 split ----------
__global__ void cbprep_kernel(const float* __restrict__ cb, _Float16* __restrict__ y,
                              float* __restrict__ c2p) {
    const int r = blockIdx.x;
    const int lane = threadIdx.x;  // 64
    const float* row = cb + (size_t)r * 512;
    float4 a = *(const float4*)&row[lane * 8];
    float4 c = *(const float4*)&row[lane * 8 + 4];
    float s = a.x * a.x + a.y * a.y + a.z * a.z + a.w * a.w
            + c.x * c.x + c.y * c.y + c.z * c.z + c.w * c.w;
#pragma unroll
    for (int off = 32; off > 0; off >>= 1) s += __shfl_down(s, off, 64);
    if (lane == 0) c2p[r] = s * 524288.f;  // 2^19

    const float e[8] = {a.x, a.y, a.z, a.w, c.x, c.y, c.z, c.w};
    half8 hv, lv;
#pragma unroll
    for (int i = 0; i < 8; ++i) {
        float v = e[i] * 1024.f;
        _Float16 h = (_Float16)v;
        hv[i] = h;
        lv[i] = (_Float16)(v - (float)h);
    }
    *(half8*)(y + (size_t)r * 1024 + lane * 8) = hv;
    *(half8*)(y + (size_t)r * 1024 + 512 + lane * 8) = lv;
}

// ---------------- MFMA cross-GEMM + fused argmin, 256l x 256v block tile -----------
// 512 threads / 8 waves (2 waves/SIMD at 1 block/CU). Wave tile 64l x 128v (acc 4x8).
// Full V=2048 per block over 8 vt iterations; grid = 16x4x4 = 256 blocks = 1 round.
// acc = Ahi*Bhi + Alo*Bhi + Ahi*Blo = 2^20*cross; key = acc - c2*2^19 (argmax).
// Both A and B tiles LDS double-buffered (2 x 64 KB = 128 KB + 4 KB slots):
//   vmcnt(0); barrier; STAGE(t+1 -> buf^1); sched_barrier; ds_read frags(buf[cur]);
//   96 MFMA. Stage flight is hidden under the MFMA cluster; writes never target the
//   buffer being read (race-free by construction).
// Tiles: linear LDS dest + XOR-swizzled global source segment + same XOR on read.
__global__ __launch_bounds__(512, 2) void cross_mfma_kernel(
    const _Float16* __restrict__ Af, const _Float16* __restrict__ Bf,
    const float* __restrict__ c2p,
    int* __restrict__ tok_i, float* __restrict__ tok_f) {

    __shared__ _Float16 AsH[2][256 * 32], AsL[2][256 * 32];   // 16 KB per plane per buf
    __shared__ _Float16 BsH[2][256 * 32], BsL[2][256 * 32];   // 16 KB per plane per buf
    __shared__ float slotv[2][256];
    __shared__ int   sloti[2][256];

    const int tid  = threadIdx.x;
    const int wave = tid >> 6;        // 0..7
    const int lane = tid & 63;
    const int wm = wave >> 1;         // 0..3: 64-row band
    const int wn = wave & 1;          // 0..1: 128-col band
    const int q  = lane >> 4;
    const int cl = lane & 15;

    const int l0 = blockIdx.x * 256;
    const int k  = blockIdx.y;
    const int b  = blockIdx.z;

    const _Float16* Ab = Af + (size_t)(b * L3V + l0) * 1024;
    const _Float16* Bb = Bf + (size_t)k * VOCABV * 1024;

    if (tid < 256) {
        slotv[0][tid] = -3.4e38f; slotv[1][tid] = -3.4e38f;
        sloti[0][tid] = 0;        sloti[1][tid] = 0;
    }

    const int rsub = tid >> 2;       // 0..127: row within 128-row staging pass
    const int seg  = tid & 3;        // 16B segment within 64B row
    const int soff = (seg ^ ((rsub >> 1) & 3)) * 8;  // swizzled source offset (halfs)
    const int rq   = (q ^ ((cl >> 1) & 3)) * 8;      // swizzled read offset (halfs)

    // 8 gload_lds per thread per step: A (2 passes x 2 planes) + B (2 x 2)
#define STAGE(BUF, VT, KO) do { \
    const _Float16* Bt_ = Bb + (size_t)((VT) * 256) * 1024; \
    _Pragma("unroll") \
    for (int i_ = 0; i_ < 2; ++i_) { \
        const _Float16* ga_ = Ab + (size_t)(i_ * 128 + rsub) * 1024 + (KO) + soff; \
        gload_lds16(ga_,       (char*)&AsH[BUF][0] + i_ * 8192 + tid * 16); \
        gload_lds16(ga_ + 512, (char*)&AsL[BUF][0] + i_ * 8192 + tid * 16); \
        const _Float16* gb_ = Bt_ + (size_t)(i_ * 128 + rsub) * 1024 + (KO) + soff; \
        gload_lds16(gb_,       (char*)&BsH[BUF][0] + i_ * 8192 + tid * 16); \
        gload_lds16(gb_ + 512, (char*)&BsL[BUF][0] + i_ * 8192 + tid * 16); \
    } \
} while (0)

    int cur = 0;
    STAGE(0, 0, 0);

#pragma unroll 1
    for (int vt = 0; vt < 8; ++vt) {
        floatx4 acc[4][8];
#pragma unroll
        for (int mt = 0; mt < 4; ++mt)
#pragma unroll
            for (int nt = 0; nt < 8; ++nt) acc[mt][nt] = (floatx4){0.f, 0.f, 0.f, 0.f};

#pragma unroll 1
        for (int ko = 0; ko < 512; ko += 32) {
            asm volatile("s_waitcnt vmcnt(0)" ::: "memory");
            __syncthreads();           // buf[cur] staged; prev reads all consumed

            // issue next tile into the other buffer; flight hidden by MFMA below
            if (ko + 32 < 512)      STAGE(cur ^ 1, vt, ko + 32);
            else if (vt + 1 < 8)    STAGE(cur ^ 1, vt + 1, 0);
            __builtin_amdgcn_sched_barrier(0);

            half8 ah[4], al[4];
#pragma unroll
            for (int mt = 0; mt < 4; ++mt) {
                const int ro = (wm * 64 + mt * 16 + cl) * 32 + rq;
                ah[mt] = *(const half8*)&AsH[cur][ro];
                al[mt] = *(const half8*)&AsL[cur][ro];
            }
#pragma unroll
            for (int nt = 0; nt < 8; ++nt) {
                const int ro = (wn * 128 + nt * 16 + cl) * 32 + rq;
                half8 bh = *(const half8*)&BsH[cur][ro];
                half8 bl = *(const half8*)&BsL[cur][ro];
#pragma unroll
                for (int mt = 0; mt < 4; ++mt) {
                    acc[mt][nt] = __builtin_amdgcn_mfma_f32_16x16x32_f16(ah[mt], bh, acc[mt][nt], 0, 0, 0);
                    acc[mt][nt] = __builtin_amdgcn_mfma_f32_16x16x32_f16(al[mt], bh, acc[mt][nt], 0, 0, 0);
                    acc[mt][nt] = __builtin_amdgcn_mfma_f32_16x16x32_f16(ah[mt], bl, acc[mt][nt], 0, 0, 0);
                }
            }
            cur ^= 1;
        }

        // per-vt argmax epilogue
        float c2v[8];
#pragma unroll
        for (int nt = 0; nt < 8; ++nt)
            c2v[nt] = c2p[k * VOCABV + vt * 256 + wn * 128 + nt * 16 + cl];
#pragma unroll
        for (int mt = 0; mt < 4; ++mt)
#pragma unroll
            for (int r = 0; r < 4; ++r) {
                float bv = acc[mt][0][r] - c2v[0];
                int   bi = vt * 256 + wn * 128 + cl;
#pragma unroll
                for (int nt = 1; nt < 8; ++nt) {
                    float m = acc[mt][nt][r] - c2v[nt];
                    int   vi = vt * 256 + wn * 128 + nt * 16 + cl;
                    if (m > bv) { bv = m; bi = vi; }
                }
#pragma unroll
                for (int msk = 1; msk < 16; msk <<= 1) {
                    float ov = __shfl_xor(bv, msk, 64);
                    int   oi = __shfl_xor(bi, msk, 64);
                    if (ov > bv || (ov == bv && oi < bi)) { bv = ov; bi = oi; }
                }
                if (cl == 0) {
                    const int row = wm * 64 + mt * 16 + q * 4 + r;
                    float cur_v = slotv[wn][row];
                    int   ci  = sloti[wn][row];
                    if (bv > cur_v || (bv == cur_v && bi < ci)) {
                        slotv[wn][row] = bv;
                        sloti[wn][row] = bi;
                    }
                }
            }
    }
#undef STAGE

    __syncthreads();
    if (tid < 256) {
        float v0 = slotv[0][tid], v1 = slotv[1][tid];
        int   i0 = sloti[0][tid], i1 = sloti[1][tid];
        bool t1 = (v1 > v0);  // wn=1 indices always larger: ties keep wn=0
        int best = t1 ? i1 : i0;
        const int n = (b * KCB + k) * L3V + l0 + tid;
        tok_i[n] = best;
        tok_f[n] = (float)best;
    }
}

// ---------------- embedding mean over 4 codebooks ----------------
__global__ void emb_kernel(const int* __restrict__ tokens, const float* __restrict__ E,
                           float* __restrict__ out) {
    const int l = blockIdx.x;
    const int b = blockIdx.y;
    const int h4 = threadIdx.x * 4;
    const int t0 = tokens[((size_t)(b * KCB + 0)) * L3V + l];
    const int t1 = tokens[((size_t)(b * KCB + 1)) * L3V + l];
    const int t2 = tokens[((size_t)(b * KCB + 2)) * L3V + l];
    const int t3 = tokens[((size_t)(b * KCB + 3)) * L3V + l];
    const float4 e0 = *(const float4*)&E[(size_t)t0 * 512 + h4];
    const float4 e1 = *(const float4*)&E[(size_t)t1 * 512 + h4];
    const float4 e2 = *(const float4*)&E[(size_t)t2 * 512 + h4];
    const float4 e3 = *(const float4*)&E[(size_t)t3 * 512 + h4];
    float4 r;
    r.x = (e0.x + e1.x + e2.x + e3.x) * 0.25f;
    r.y = (e0.y + e1.y + e2.y + e3.y) * 0.25f;
    r.z = (e0.z + e1.z + e2.z + e3.z) * 0.25f;
    r.w = (e0.w + e1.w + e2.w + e3.w) * 0.25f;
    *(float4*)&out[((size_t)b * L3V + l) * 512 + h4] = r;
}

extern "C" void kernel_launch(void* const* d_in, const int* in_sizes, int n_in,
                              void* d_out, int out_size, void* d_ws, size_t ws_size,
                              hipStream_t stream) {
    const float* audio = (const float*)d_in[0];
    const float* w1 = (const float*)d_in[1];
    const float* b1 = (const float*)d_in[2];
    const float* w2 = (const float*)d_in[3];
    const float* b2 = (const float*)d_in[4];
    const float* w3 = (const float*)d_in[5];
    const float* b3 = (const float*)d_in[6];
    const float* cb = (const float*)d_in[7];
    const float* E  = (const float*)d_in[8];

    float* out_tok = (float*)d_out;
    float* out_emb = out_tok + (size_t)B_ * KCB * L3V;

    float* ws = (float*)d_ws;
    size_t off = 0;
    float* x1  = ws + off; off += (size_t)B_ * C1V * L1V;            // conv1 out, later Afh
    float* x2f = ws + off; off += (size_t)B_ * C2V * L2V / 2;        // conv2 out
    float* bfh_f = ws + off; off += (size_t)KCB * VOCABV * 1024 / 2; // Bfh
    float* w2h_f = ws + off; off += (size_t)C2V * (C1V * 8) / 2;
    float* w2l_f = ws + off; off += (size_t)C2V * (C1V * 8) / 2;
    float* w3h_f = ws + off; off += (size_t)C3V * (C2V * 8) / 2;
    float* w3l_f = ws + off; off += (size_t)C3V * (C2V * 8) / 2;
    float* c2p = ws + off; off += (size_t)KCB * VOCABV;
    int*   tok = (int*)(ws + off); off += (size_t)B_ * KCB * L3V;

    _Float16* Afh = (_Float16*)x1;   // conv3 writes over x1 (dead after conv2)
    _Float16* Bfh = (_Float16*)bfh_f;
    _Float16* W2H = (_Float16*)w2h_f; _Float16* W2L = (_Float16*)w2l_f;
    _Float16* W3H = (_Float16*)w3h_f; _Float16* W3L = (_Float16*)w3l_f;

    wsplit_kernel<<<(C2V * C1V + 255) / 256, 256, 0, stream>>>(w2, W2H, W2L, C1V, C2V);
    wsplit_kernel<<<(C3V * C2V + 255) / 256, 256, 0, stream>>>(w3, W3H, W3L, C2V, C3V);

    conv1_kernel<<<dim3(L1V / 256, C1V, B_), 256, 0, stream>>>(audio, w1, b1, x1);

    conv2_mfma_kernel<<<dim3(L2V / 128, C2V / 128, B_), 256, 0, stream>>>(
        x1, W2H, W2L, b2, x2f);

    conv3_mfma_kernel<<<dim3(L2V / 256 * 2 / 2, C3V / 128, B_) /* = (L3V/128, C3V/128, B_) */, 256, 0, stream>>>(
        x2f, W3H, W3L, b3, Afh);

    cbprep_kernel<<<KCB * VOCABV, 64, 0, stream>>>(cb, Bfh, c2p);

    cross_mfma_kernel<<<dim3(L3V / 256, KCB, B_), 512, 0, stream>>>(
        Afh, Bfh, c2p, tok, out_tok);

    emb_kernel<<<dim3(L3V, B_), 128, 0, stream>>>(tok, E, out_emb);
}

// Round 6
// 734.935 us; speedup vs baseline: 1.2919x; 1.0679x over previous
//
#include <hip/hip_runtime.h>
#include <hip/hip_bf16.h>
#include <stdint.h>

#define B_ 4
#define S_IN 32768
#define C1V 128
#define L1V 16384
#define C2V 256
#define L2V 8192
#define C3V 512
#define L3V 4096
#define VOCABV 2048
#define KCB 4

typedef _Float16 half8 __attribute__((ext_vector_type(8)));
typedef float floatx4 __attribute__((ext_vector_type(4)));

#define AS1 __attribute__((address_space(1)))
#define AS3 __attribute__((address_space(3)))

__device__ __forceinline__ void gload_lds16(const void* g, void* l) {
    __builtin_amdgcn_global_load_lds((const AS1 void*)g, (AS3 void*)l, 16, 0, 0);
}

// read 8 halfs at a 4B-aligned LDS address (4x ds_read_b32)
__device__ __forceinline__ half8 lds_read_half8_a4(const _Float16* p) {
    union { uint32_t u[4]; half8 h; } t;
    const uint32_t* w = (const uint32_t*)p;
    t.u[0] = w[0]; t.u[1] = w[1]; t.u[2] = w[2]; t.u[3] = w[3];
    return t.h;
}

// ---------------- conv1: [B,1,S] -> [B,128,16384], k=7 s=2 p=3, relu ----------------
__global__ void conv1_kernel(const float* __restrict__ x, const float* __restrict__ w,
                             const float* __restrict__ bias, float* __restrict__ out) {
    __shared__ float xs[2 * 256 + 6];
    __shared__ float ws[7];
    const int l0 = blockIdx.x * 256;
    const int co = blockIdx.y;
    const int b  = blockIdx.z;
    const int tid = threadIdx.x;
    const float* xb = x + (size_t)b * S_IN;
    for (int n = tid; n < 2 * 256 + 6; n += 256) {
        int p = 2 * l0 - 3 + n;
        xs[n] = (p >= 0 && p < S_IN) ? xb[p] : 0.f;
    }
    if (tid < 7) ws[tid] = w[co * 7 + tid];
    __syncthreads();
    float acc = bias[co];
    const int base = 2 * tid;
#pragma unroll
    for (int t = 0; t < 7; ++t) acc = fmaf(ws[t], xs[base + t], acc);
    acc = fmaxf(acc, 0.f);
    out[((size_t)(b * C1V + co)) * L1V + l0 + tid] = acc;
}

// ---------------- weight prep: w[co][ci][7] fp32 -> hi/lo f16 planes [co][ci*8+u] ----
__global__ void wsplit_kernel(const float* __restrict__ w, _Float16* __restrict__ wh,
                              _Float16* __restrict__ wl, int cin, int cout) {
    int idx = blockIdx.x * 256 + threadIdx.x;
    if (idx >= cin * cout) return;
    int co = idx / cin;
    int ci = idx - co * cin;
    const float* src = w + ((size_t)co * cin + ci) * 7;
    half8 h, l;
    h[0] = (_Float16)0.f; l[0] = (_Float16)0.f;
#pragma unroll
    for (int u = 1; u < 8; ++u) {
        float v = src[u - 1] * 1024.f;
        _Float16 hh = (_Float16)v;
        h[u] = hh;
        l[u] = (_Float16)(v - (float)hh);
    }
    size_t o = (size_t)co * (cin * 8) + ci * 8;
    *(half8*)(wh + o) = h;
    *(half8*)(wl + o) = l;
}

// ---------------- conv2 via f16 3-product MFMA: A=W (m=co), B=X windows (n=l) -------
__global__ __launch_bounds__(256, 2) void conv2_mfma_kernel(
    const float* __restrict__ in, const _Float16* __restrict__ WH,
    const _Float16* __restrict__ WL, const float* __restrict__ bias,
    float* __restrict__ out) {
    __shared__ _Float16 XsH[4 * 272], XsL[4 * 272];
    __shared__ _Float16 WsH[128 * 32], WsL[128 * 32];
    const int tid = threadIdx.x;
    const int wave = tid >> 6;
    const int lane = tid & 63;
    const int wm = wave >> 1, wn = wave & 1;
    const int q  = lane >> 4;
    const int cl = lane & 15;
    const int l0  = blockIdx.x * 128;
    const int co0 = blockIdx.y * 128;
    const int b   = blockIdx.z;
    const float* inb = in + (size_t)b * C1V * L1V;

    const int wrow  = lane >> 2;
    const int wseg  = lane & 3;
    const int wsoff = (wseg ^ ((wrow >> 1) & 3)) * 8;   // swizzled source offset (halfs)
    const int rq    = (q ^ ((cl >> 1) & 3)) * 8;        // swizzled read offset (halfs)

    floatx4 acc[4][4];
#pragma unroll
    for (int a = 0; a < 4; ++a)
#pragma unroll
        for (int n = 0; n < 4; ++n) acc[a][n] = (floatx4){0.f, 0.f, 0.f, 0.f};

    for (int ch = 0; ch < 32; ++ch) {
        __syncthreads();
        for (int n = tid; n < 4 * 264; n += 256) {
            int ci = n / 264;
            int m  = n - ci * 264;
            int p  = 2 * l0 - 4 + m;
            float v = (p >= 0 && p < L1V) ? inb[(size_t)(ch * 4 + ci) * L1V + p] * 1024.f : 0.f;
            _Float16 h = (_Float16)v;
            XsH[ci * 272 + m] = h;
            XsL[ci * 272 + m] = (_Float16)(v - (float)h);
        }
        const int k0 = ch * 32;
        for (int g = wave; g < 8; g += 4) {
            const _Float16* gh = WH + (size_t)(co0 + g * 16 + wrow) * 1024 + k0 + wsoff;
            const _Float16* gl = WL + (size_t)(co0 + g * 16 + wrow) * 1024 + k0 + wsoff;
            gload_lds16(gh, (char*)WsH + g * 1024);
            gload_lds16(gl, (char*)WsL + g * 1024);
        }
        asm volatile("s_waitcnt vmcnt(0)" ::: "memory");
        __syncthreads();

        half8 awh[4], awl[4], bxh[4], bxl[4];
#pragma unroll
        for (int a = 0; a < 4; ++a) {
            const int ro = (wm * 64 + a * 16 + cl) * 32 + rq;
            awh[a] = *(const half8*)&WsH[ro];
            awl[a] = *(const half8*)&WsL[ro];
        }
#pragma unroll
        for (int n = 0; n < 4; ++n) {
            const int lrel = wn * 64 + n * 16 + cl;
            bxh[n] = lds_read_half8_a4(&XsH[q * 272 + 2 * lrel]);
            bxl[n] = lds_read_half8_a4(&XsL[q * 272 + 2 * lrel]);
        }
#pragma unroll
        for (int a = 0; a < 4; ++a)
#pragma unroll
            for (int n = 0; n < 4; ++n) {
                acc[a][n] = __builtin_amdgcn_mfma_f32_16x16x32_f16(awh[a], bxh[n], acc[a][n], 0, 0, 0);
                acc[a][n] = __builtin_amdgcn_mfma_f32_16x16x32_f16(awl[a], bxh[n], acc[a][n], 0, 0, 0);
                acc[a][n] = __builtin_amdgcn_mfma_f32_16x16x32_f16(awh[a], bxl[n], acc[a][n], 0, 0, 0);
            }
    }

    float bv[4][4];
#pragma unroll
    for (int a = 0; a < 4; ++a)
#pragma unroll
        for (int r = 0; r < 4; ++r) bv[a][r] = bias[co0 + wm * 64 + a * 16 + q * 4 + r];
#pragma unroll
    for (int a = 0; a < 4; ++a)
#pragma unroll
        for (int n = 0; n < 4; ++n) {
            const int l = l0 + wn * 64 + n * 16 + cl;
#pragma unroll
            for (int r = 0; r < 4; ++r) {
                const int co = co0 + wm * 64 + a * 16 + q * 4 + r;
                float vv = fmaxf(acc[a][n][r] * (1.f / 1048576.f) + bv[a][r], 0.f);
                out[((size_t)(b * C2V + co)) * L2V + l] = vv;
            }
        }
}

// ---------------- conv3 via f16 3-product MFMA: A=X windows (m=l), B=W (n=co) -------
__global__ __launch_bounds__(256, 2) void conv3_mfma_kernel(
    const float* __restrict__ in, const _Float16* __restrict__ WH,
    const _Float16* __restrict__ WL, const float* __restrict__ bias,
    _Float16* __restrict__ outh) {
    __shared__ _Float16 XsH[4 * 272], XsL[4 * 272];
    __shared__ _Float16 WsH[128 * 32], WsL[128 * 32];
    const int tid = threadIdx.x;
    const int wave = tid >> 6;
    const int lane = tid & 63;
    const int wm = wave >> 1, wn = wave & 1;
    const int q  = lane >> 4;
    const int cl = lane & 15;
    const int l0  = blockIdx.x * 128;
    const int co0 = blockIdx.y * 128;
    const int b   = blockIdx.z;
    const float* inb = in + (size_t)b * C2V * L2V;

    const int wrow  = lane >> 2;
    const int wseg  = lane & 3;
    const int wsoff = (wseg ^ ((wrow >> 1) & 3)) * 8;
    const int rq    = (q ^ ((cl >> 1) & 3)) * 8;

    floatx4 acc[4][4];
#pragma unroll
    for (int a = 0; a < 4; ++a)
#pragma unroll
        for (int n = 0; n < 4; ++n) acc[a][n] = (floatx4){0.f, 0.f, 0.f, 0.f};

    for (int ch = 0; ch < 64; ++ch) {
        __syncthreads();
        for (int n = tid; n < 4 * 264; n += 256) {
            int ci = n / 264;
            int m  = n - ci * 264;
            int p  = 2 * l0 - 4 + m;
            float v = (p >= 0 && p < L2V) ? inb[(size_t)(ch * 4 + ci) * L2V + p] * 1024.f : 0.f;
            _Float16 h = (_Float16)v;
            XsH[ci * 272 + m] = h;
            XsL[ci * 272 + m] = (_Float16)(v - (float)h);
        }
        const int k0 = ch * 32;
        for (int g = wave; g < 8; g += 4) {
            const _Float16* gh = WH + (size_t)(co0 + g * 16 + wrow) * 2048 + k0 + wsoff;
            const _Float16* gl = WL + (size_t)(co0 + g * 16 + wrow) * 2048 + k0 + wsoff;
            gload_lds16(gh, (char*)WsH + g * 1024);
            gload_lds16(gl, (char*)WsL + g * 1024);
        }
        asm volatile("s_waitcnt vmcnt(0)" ::: "memory");
        __syncthreads();

        half8 axh[4], axl[4], bwh[4], bwl[4];
#pragma unroll
        for (int a = 0; a < 4; ++a) {
            const int lrel = wm * 64 + a * 16 + cl;
            axh[a] = lds_read_half8_a4(&XsH[q * 272 + 2 * lrel]);
            axl[a] = lds_read_half8_a4(&XsL[q * 272 + 2 * lrel]);
        }
#pragma unroll
        for (int n = 0; n < 4; ++n) {
            const int ro = (wn * 64 + n * 16 + cl) * 32 + rq;
            bwh[n] = *(const half8*)&WsH[ro];
            bwl[n] = *(const half8*)&WsL[ro];
        }
#pragma unroll
        for (int a = 0; a < 4; ++a)
#pragma unroll
            for (int n = 0; n < 4; ++n) {
                acc[a][n] = __builtin_amdgcn_mfma_f32_16x16x32_f16(axh[a], bwh[n], acc[a][n], 0, 0, 0);
                acc[a][n] = __builtin_amdgcn_mfma_f32_16x16x32_f16(axl[a], bwh[n], acc[a][n], 0, 0, 0);
                acc[a][n] = __builtin_amdgcn_mfma_f32_16x16x32_f16(axh[a], bwl[n], acc[a][n], 0, 0, 0);
            }
    }

    float bv[4];
#pragma unroll
    for (int n = 0; n < 4; ++n) bv[n] = bias[co0 + wn * 64 + n * 16 + cl];
#pragma unroll
    for (int a = 0; a < 4; ++a)
#pragma unroll
        for (int n = 0; n < 4; ++n) {
            const int co = co0 + wn * 64 + n * 16 + cl;
#pragma unroll
            for (int r = 0; r < 4; ++r) {
                const int l = l0 + wm * 64 + a * 16 + q * 4 + r;
                float f = acc[a][n][r] * (1.f / 1048576.f) + bv[n];
                float s = f * 1024.f;
                _Float16 h = (_Float16)s;
                _Float16 lo = (_Float16)(s - (float)h);
                _Float16* dst = outh + ((size_t)b * L3V + l) * 1024 + co;
                dst[0] = h;
                dst[512] = lo;
            }
        }
}

// ---------------- fused codebook prep: rowsq*2^19 + x1024 hi/lo f16 split ----------
__global__ void cbprep_kernel(const float* __restrict__ cb, _Float16* __restrict__ y,
                              float* __restrict__ c2p) {
    const int r = blockIdx.x;
    const int lane = threadIdx.x;  // 64
    const float* row = cb + (size_t)r * 512;
    float4 a = *(const float4*)&row[lane * 8];
    float4 c = *(const float4*)&row[lane * 8 + 4];
    float s = a.x * a.x + a.y * a.y + a.z * a.z + a.w * a.w
            + c.x * c.x + c.y * c.y + c.z * c.z + c.w * c.w;
#pragma unroll
    for (int off = 32; off > 0; off >>= 1) s += __shfl_down(s, off, 64);
    if (lane == 0) c2p[r] = s * 524288.f;  // 2^19

    const float e[8] = {a.x, a.y, a.z, a.w, c.x, c.y, c.z, c.w};
    half8 hv, lv;
#pragma unroll
    for (int i = 0; i < 8; ++i) {
        float v = e[i] * 1024.f;
        _Float16 h = (_Float16)v;
        hv[i] = h;
        lv[i] = (_Float16)(v - (float)h);
    }
    *(half8*)(y + (size_t)r * 1024 + lane * 8) = hv;
    *(half8*)(y + (size_t)r * 1024 + 512 + lane * 8) = lv;
}

// ---------------- MFMA cross-GEMM + fused argmin, 256l x 256v, 4-phase schedule ----
// 512 thr / 8 waves, wave tile 64l x 128v (acc 4x8). BK=32 hi/lo (=64 KB/step), dbuf.
// Per K-step: 4 phases. Phase p: vmcnt(Np) [counted: 3,4,5,6, never 0]; raw s_barrier;
// ds_read {A frags (ph0) + B chunk p}; issue 2 gload_lds of step t+1 chunk p;
// lgkmcnt(0); sched_barrier; setprio(1); 24 MFMA (nt=2p,2p+1); setprio(0); SB.
// Thread's 8 stage loads/step ordered [a0,a1|a2,a3|b0,b1|b2,b3] -> derived vmcnt.
// B LDS layout per plane/buf: [chunk p(4)][g=wn(2)][j(32)][32 halfs], chunk = rows
// {32p..32p+31} u {128+32p..}; contiguous 8KB per chunk = linear gload_lds target.
// Swizzle: source seg ^= (row>>1)&3 (== (lane>>3)&3 for stage, (cl>>1)&3 for read).
// c2 cached in LDS at prologue (epilogue has no VMEM -> vmcnt counts stay exact).
__global__ __launch_bounds__(512, 2) void cross_mfma_kernel(
    const _Float16* __restrict__ Af, const _Float16* __restrict__ Bf,
    const float* __restrict__ c2p,
    int* __restrict__ tok_i, float* __restrict__ tok_f) {

    __shared__ _Float16 AsH[2][8192], AsL[2][8192];   // 16 KB per plane per buf
    __shared__ _Float16 BsH[2][8192], BsL[2][8192];   // 16 KB per plane per buf
    __shared__ float c2s[2048];
    __shared__ float slotv[2][256];
    __shared__ int   sloti[2][256];

    const int tid  = threadIdx.x;
    const int w    = tid >> 6;        // 0..7
    const int lane = tid & 63;
    const int wm = w >> 1;            // 0..3: 64-row band
    const int wn = w & 1;             // 0..1: 128-col band
    const int q  = lane >> 4;
    const int cl = lane & 15;

    const int l0 = blockIdx.x * 256;
    const int k  = blockIdx.y;
    const int b  = blockIdx.z;

    const _Float16* Ab = Af + (size_t)(b * L3V + l0) * 1024;
    const _Float16* Bb = Bf + (size_t)k * VOCABV * 1024;

    // prologue: c2 -> LDS; slot init
    {
        float4 cv = *(const float4*)&c2p[k * VOCABV + tid * 4];
        *(float4*)&c2s[tid * 4] = cv;
    }
    if (tid < 256) {
        slotv[0][tid] = -3.4e38f; slotv[1][tid] = -3.4e38f;
        sloti[0][tid] = 0;        sloti[1][tid] = 0;
    }

    // staging geometry (per-lane constants)
    const int arow  = w * 16 + (lane >> 2);            // A: row within 128-half
    const int bg    = (w >> 1) & 1;                    // B: wn-group
    const int bj    = (w & 1) * 16 + (lane >> 2);      // B: row within 32-group
    const int bpl   = w >> 2;                          // B: plane (0=hi,1=lo)
    const int sswz8 = ((lane & 3) ^ ((lane >> 3) & 3)) * 8;  // swizzled src seg (halfs)
    const int brq   = (q ^ ((cl >> 1) & 3)) * 8;       // swizzled read seg (halfs)

    // A load (PL=plane, H=row-half) -> As{H,L}[NXT]; dest linear per wave
#define STAGE_A(NXT, KON, PL, H) do { \
    const _Float16* s_ = Ab + (size_t)((H) * 128 + arow) * 1024 + (PL) * 512 + (KON) + sswz8; \
    gload_lds16(s_, ((PL) ? (char*)&AsL[NXT][0] : (char*)&AsH[NXT][0]) \
                     + (H) * 8192 + w * 1024 + lane * 16); \
} while (0)
    // B load chunk C -> Bs{H,L}[NXT] chunk C; plane by wave group
#define STAGE_B(NXT, VTN, KON, C) do { \
    const _Float16* s_ = Bb + (size_t)((VTN) * 256 + 128 * bg + 32 * (C) + bj) * 1024 \
                         + bpl * 512 + (KON) + sswz8; \
    gload_lds16(s_, (bpl ? (char*)&BsL[NXT][0] : (char*)&BsH[NXT][0]) \
                     + (C) * 4096 + (w & 3) * 1024 + lane * 16); \
} while (0)

    floatx4 acc[4][8];
    half8 ah[4], al[4];
    int cur = 0;

    // stage step 0 into buf0, issue order [a0,a1 | a2,a3 | b0,b1 | b2,b3]
    STAGE_A(0, 0, 0, 0); STAGE_A(0, 0, 0, 1);
    STAGE_A(0, 0, 1, 0); STAGE_A(0, 0, 1, 1);
    STAGE_B(0, 0, 0, 0); STAGE_B(0, 0, 0, 1);
    STAGE_B(0, 0, 0, 2); STAGE_B(0, 0, 0, 3);

#define PHASE(P, VMC) do { \
    asm volatile("s_waitcnt vmcnt(" #VMC ")" ::: "memory"); \
    __builtin_amdgcn_s_barrier(); \
    if ((P) == 0) { \
        _Pragma("unroll") \
        for (int mt = 0; mt < 4; ++mt) { \
            const int aro = (wm * 64 + mt * 16 + cl) * 32 + brq; \
            ah[mt] = *(const half8*)&AsH[cur][aro]; \
            al[mt] = *(const half8*)&AsL[cur][aro]; \
        } \
    } \
    const int bro0_ = (P) * 2048 + wn * 1024 + cl * 32 + brq; \
    const int bro1_ = bro0_ + 512; \
    half8 bh0_ = *(const half8*)&BsH[cur][bro0_]; \
    half8 bl0_ = *(const half8*)&BsL[cur][bro0_]; \
    half8 bh1_ = *(const half8*)&BsH[cur][bro1_]; \
    half8 bl1_ = *(const half8*)&BsL[cur][bro1_]; \
    if ((P) == 0)      { STAGE_A(nxt, kon, 0, 0); STAGE_A(nxt, kon, 0, 1); } \
    else if ((P) == 1) { STAGE_A(nxt, kon, 1, 0); STAGE_A(nxt, kon, 1, 1); } \
    else if ((P) == 2) { STAGE_B(nxt, vtn, kon, 0); STAGE_B(nxt, vtn, kon, 1); } \
    else               { STAGE_B(nxt, vtn, kon, 2); STAGE_B(nxt, vtn, kon, 3); } \
    asm volatile("s_waitcnt lgkmcnt(0)" ::: "memory"); \
    __builtin_amdgcn_sched_barrier(0); \
    __builtin_amdgcn_s_setprio(1); \
    _Pragma("unroll") \
    for (int mt = 0; mt < 4; ++mt) { \
        acc[mt][2*(P)]   = __builtin_amdgcn_mfma_f32_16x16x32_f16(ah[mt], bh0_, acc[mt][2*(P)], 0, 0, 0); \
        acc[mt][2*(P)]   = __builtin_amdgcn_mfma_f32_16x16x32_f16(al[mt], bh0_, acc[mt][2*(P)], 0, 0, 0); \
        acc[mt][2*(P)]   = __builtin_amdgcn_mfma_f32_16x16x32_f16(ah[mt], bl0_, acc[mt][2*(P)], 0, 0, 0); \
        acc[mt][2*(P)+1] = __builtin_amdgcn_mfma_f32_16x16x32_f16(ah[mt], bh1_, acc[mt][2*(P)+1], 0, 0, 0); \
        acc[mt][2*(P)+1] = __builtin_amdgcn_mfma_f32_16x16x32_f16(al[mt], bh1_, acc[mt][2*(P)+1], 0, 0, 0); \
        acc[mt][2*(P)+1] = __builtin_amdgcn_mfma_f32_16x16x32_f16(ah[mt], bl1_, acc[mt][2*(P)+1], 0, 0, 0); \
    } \
    __builtin_amdgcn_s_setprio(0); \
    __builtin_amdgcn_sched_barrier(0); \
} while (0)

#pragma unroll 1
    for (int t = 0; t < 128; ++t) {
        const int nxt = cur ^ 1;
        const int tn  = t + 1;
        const int vtn = tn >> 4;                 // 8 at t=127: benign over-read
        const int kon = (tn & 15) << 5;
        const int vt  = t >> 4;

        if ((t & 15) == 0) {
#pragma unroll
            for (int mt = 0; mt < 4; ++mt)
#pragma unroll
                for (int nt = 0; nt < 8; ++nt) acc[mt][nt] = (floatx4){0.f, 0.f, 0.f, 0.f};
        }

        { PHASE(0, 3); }
        { PHASE(1, 4); }
        { PHASE(2, 5); }
        { PHASE(3, 6); }
        cur = nxt;

        if ((t & 15) == 15) {
            // per-vt argmax epilogue (c2 from LDS; no VMEM here)
            float c2v[8];
#pragma unroll
            for (int nt = 0; nt < 8; ++nt)
                c2v[nt] = c2s[vt * 256 + wn * 128 + nt * 16 + cl];
#pragma unroll
            for (int mt = 0; mt < 4; ++mt)
#pragma unroll
                for (int r = 0; r < 4; ++r) {
                    float bv = acc[mt][0][r] - c2v[0];
                    int   bi = vt * 256 + wn * 128 + cl;
#pragma unroll
                    for (int nt = 1; nt < 8; ++nt) {
                        float m = acc[mt][nt][r] - c2v[nt];
                        int   vi = vt * 256 + wn * 128 + nt * 16 + cl;
                        if (m > bv) { bv = m; bi = vi; }
                    }
#pragma unroll
                    for (int msk = 1; msk < 16; msk <<= 1) {
                        float ov = __shfl_xor(bv, msk, 64);
                        int   oi = __shfl_xor(bi, msk, 64);
                        if (ov > bv || (ov == bv && oi < bi)) { bv = ov; bi = oi; }
                    }
                    if (cl == 0) {
                        const int row = wm * 64 + mt * 16 + q * 4 + r;
                        float cur_v = slotv[wn][row];
                        int   ci  = sloti[wn][row];
                        if (bv > cur_v || (bv == cur_v && bi < ci)) {
                            slotv[wn][row] = bv;
                            sloti[wn][row] = bi;
                        }
                    }
                }
        }
    }
#undef PHASE
#undef STAGE_A
#undef STAGE_B

    __syncthreads();
    if (tid < 256) {
        float v0 = slotv[0][tid], v1 = slotv[1][tid];
        int   i0 = sloti[0][tid], i1 = sloti[1][tid];
        bool t1 = (v1 > v0);  // wn=1 indices always larger: ties keep wn=0
        int best = t1 ? i1 : i0;
        const int n = (b * KCB + k) * L3V + l0 + tid;
        tok_i[n] = best;
        tok_f[n] = (float)best;
    }
}

// ---------------- embedding mean over 4 codebooks ----------------
__global__ void emb_kernel(const int* __restrict__ tokens, const float* __restrict__ E,
                           float* __restrict__ out) {
    const int l = blockIdx.x;
    const int b = blockIdx.y;
    const int h4 = threadIdx.x * 4;
    const int t0 = tokens[((size_t)(b * KCB + 0)) * L3V + l];
    const int t1 = tokens[((size_t)(b * KCB + 1)) * L3V + l];
    const int t2 = tokens[((size_t)(b * KCB + 2)) * L3V + l];
    const int t3 = tokens[((size_t)(b * KCB + 3)) * L3V + l];
    const float4 e0 = *(const float4*)&E[(size_t)t0 * 512 + h4];
    const float4 e1 = *(const float4*)&E[(size_t)t1 * 512 + h4];
    const float4 e2 = *(const float4*)&E[(size_t)t2 * 512 + h4];
    const float4 e3 = *(const float4*)&E[(size_t)t3 * 512 + h4];
    float4 r;
    r.x = (e0.x + e1.x + e2.x + e3.x) * 0.25f;
    r.y = (e0.y + e1.y + e2.y + e3.y) * 0.25f;
    r.z = (e0.z + e1.z + e2.z + e3.z) * 0.25f;
    r.w = (e0.w + e1.w + e2.w + e3.w) * 0.25f;
    *(float4*)&out[((size_t)b * L3V + l) * 512 + h4] = r;
}

extern "C" void kernel_launch(void* const* d_in, const int* in_sizes, int n_in,
                              void* d_out, int out_size, void* d_ws, size_t ws_size,
                              hipStream_t stream) {
    const float* audio = (const float*)d_in[0];
    const float* w1 = (const float*)d_in[1];
    const float* b1 = (const float*)d_in[2];
    const float* w2 = (const float*)d_in[3];
    const float* b2 = (const float*)d_in[4];
    const float* w3 = (const float*)d_in[5];
    const float* b3 = (const float*)d_in[6];
    const float* cb = (const float*)d_in[7];
    const float* E  = (const float*)d_in[8];

    float* out_tok = (float*)d_out;
    float* out_emb = out_tok + (size_t)B_ * KCB * L3V;

    float* ws = (float*)d_ws;
    size_t off = 0;
    float* x1  = ws + off; off += (size_t)B_ * C1V * L1V;            // conv1 out, later Afh
    float* x2f = ws + off; off += (size_t)B_ * C2V * L2V / 2;        // conv2 out
    float* bfh_f = ws + off; off += (size_t)KCB * VOCABV * 1024 / 2; // Bfh
    float* w2h_f = ws + off; off += (size_t)C2V * (C1V * 8) / 2;
    float* w2l_f = ws + off; off += (size_t)C2V * (C1V * 8) / 2;
    float* w3h_f = ws + off; off += (size_t)C3V * (C2V * 8) / 2;
    float* w3l_f = ws + off; off += (size_t)C3V * (C2V * 8) / 2;
    float* c2p = ws + off; off += (size_t)KCB * VOCABV;
    int*   tok = (int*)(ws + off); off += (size_t)B_ * KCB * L3V;

    _Float16* Afh = (_Float16*)x1;   // conv3 writes over x1 (dead after conv2)
    _Float16* Bfh = (_Float16*)bfh_f;
    _Float16* W2H = (_Float16*)w2h_f; _Float16* W2L = (_Float16*)w2l_f;
    _Float16* W3H = (_Float16*)w3h_f; _Float16* W3L = (_Float16*)w3l_f;

    wsplit_kernel<<<(C2V * C1V + 255) / 256, 256, 0, stream>>>(w2, W2H, W2L, C1V, C2V);
    wsplit_kernel<<<(C3V * C2V + 255) / 256, 256, 0, stream>>>(w3, W3H, W3L, C2V, C3V);

    conv1_kernel<<<dim3(L1V / 256, C1V, B_), 256, 0, stream>>>(audio, w1, b1, x1);

    conv2_mfma_kernel<<<dim3(L2V / 128, C2V / 128, B_), 256, 0, stream>>>(
        x1, W2H, W2L, b2, x2f);

    conv3_mfma_kernel<<<dim3(L3V / 128, C3V / 128, B_), 256, 0, stream>>>(
        x2f, W3H, W3L, b3, Afh);

    cbprep_kernel<<<KCB * VOCABV, 64, 0, stream>>>(cb, Bfh, c2p);

    cross_mfma_kernel<<<dim3(L3V / 256, KCB, B_), 512, 0, stream>>>(
        Afh, Bfh, c2p, tok, out_tok);

    emb_kernel<<<dim3(L3V, B_), 128, 0, stream>>>(tok, E, out_emb);
}

// Round 7
// 595.670 us; speedup vs baseline: 1.5939x; 1.2338x over previous
//
#include <hip/hip_runtime.h>
#include <hip/hip_bf16.h>
#include <stdint.h>

#define B_ 4
#define S_IN 32768
#define C1V 128
#define L1V 16384
#define C2V 256
#define L2V 8192
#define C3V 512
#define L3V 4096
#define VOCABV 2048
#define KCB 4

// padded hi/lo f16 plane layout for conv activations:
// row r = b*C + c, row stride R = 2*(L+16) halfs; hi plane at [8 .. L+8), lo at +P=(L+16).
// 8-half zero pads on both sides of each plane allow unpredicated global_load_lds staging.
#define R1P (2 * (L1V + 16))
#define P1P (L1V + 16)
#define R2P (2 * (L2V + 16))
#define P2P (L2V + 16)

typedef _Float16 half8 __attribute__((ext_vector_type(8)));
typedef float floatx4 __attribute__((ext_vector_type(4)));

#define AS1 __attribute__((address_space(1)))
#define AS3 __attribute__((address_space(3)))

__device__ __forceinline__ void gload_lds16(const void* g, void* l) {
    __builtin_amdgcn_global_load_lds((const AS1 void*)g, (AS3 void*)l, 16, 0, 0);
}

// read 8 halfs at a 4B-aligned LDS address (4x ds_read_b32)
__device__ __forceinline__ half8 lds_read_half8_a4(const _Float16* p) {
    union { uint32_t u[4]; half8 h; } t;
    const uint32_t* w = (const uint32_t*)p;
    t.u[0] = w[0]; t.u[1] = w[1]; t.u[2] = w[2]; t.u[3] = w[3];
    return t.h;
}

// ---------------- pad zeroing for x1/x2 hi-lo buffers (runs first) ----------------
__global__ void padzero_kernel(_Float16* __restrict__ x1h, _Float16* __restrict__ x2h) {
    int j = blockIdx.x * 256 + threadIdx.x;
    half8 z;
#pragma unroll
    for (int i = 0; i < 8; ++i) z[i] = (_Float16)0.f;
    if (j < 2048) {                       // B*C1V=512 rows x 4 pad-slots
        int row = j >> 2, p = j & 3;
        size_t base = (size_t)row * R1P + (size_t)(p >> 1) * P1P + ((p & 1) ? (L1V + 8) : 0);
        *(half8*)(x1h + base) = z;
    } else if (j < 6144) {                // B*C2V=1024 rows x 4 pad-slots
        int j2 = j - 2048;
        int row = j2 >> 2, p = j2 & 3;
        size_t base = (size_t)row * R2P + (size_t)(p >> 1) * P2P + ((p & 1) ? (L2V + 8) : 0);
        *(half8*)(x2h + base) = z;
    }
}

// ---------------- conv1: [B,1,S] -> padded hi/lo f16 planes, k=7 s=2 p=3, relu -----
__global__ void conv1_kernel(const float* __restrict__ x, const float* __restrict__ w,
                             const float* __restrict__ bias, _Float16* __restrict__ out) {
    __shared__ float xs[2 * 256 + 6];
    __shared__ float ws[7];
    const int l0 = blockIdx.x * 256;
    const int co = blockIdx.y;
    const int b  = blockIdx.z;
    const int tid = threadIdx.x;
    const float* xb = x + (size_t)b * S_IN;
    for (int n = tid; n < 2 * 256 + 6; n += 256) {
        int p = 2 * l0 - 3 + n;
        xs[n] = (p >= 0 && p < S_IN) ? xb[p] : 0.f;
    }
    if (tid < 7) ws[tid] = w[co * 7 + tid];
    __syncthreads();
    float acc = bias[co];
    const int base = 2 * tid;
#pragma unroll
    for (int t = 0; t < 7; ++t) acc = fmaf(ws[t], xs[base + t], acc);
    float s = fmaxf(acc, 0.f) * 1024.f;   // pre-scaled x1024, split hi/lo (exact 2^10 scale)
    _Float16 h  = (_Float16)s;
    _Float16 lo = (_Float16)(s - (float)h);
    size_t o = (size_t)(b * C1V + co) * R1P + 8 + l0 + tid;
    out[o] = h;
    out[o + P1P] = lo;
}

// ---------------- weight prep: w[co][ci][7] fp32 -> hi/lo f16 planes [co][ci*8+u] ----
__global__ void wsplit_kernel(const float* __restrict__ w, _Float16* __restrict__ wh,
                              _Float16* __restrict__ wl, int cin, int cout) {
    int idx = blockIdx.x * 256 + threadIdx.x;
    if (idx >= cin * cout) return;
    int co = idx / cin;
    int ci = idx - co * cin;
    const float* src = w + ((size_t)co * cin + ci) * 7;
    half8 h, l;
    h[0] = (_Float16)0.f; l[0] = (_Float16)0.f;
#pragma unroll
    for (int u = 1; u < 8; ++u) {
        float v = src[u - 1] * 1024.f;
        _Float16 hh = (_Float16)v;
        h[u] = hh;
        l[u] = (_Float16)(v - (float)hh);
    }
    size_t o = (size_t)co * (cin * 8) + ci * 8;
    *(half8*)(wh + o) = h;
    *(half8*)(wl + o) = l;
}

// X staging (both convs): 272 16B-segs = [pl(2)][ci(4)][sg(34)] -> flat LDS Xs[2176].
// 34 segs cover 272 halfs/row starting at window base p = 2*l0-8 (buffer idx 2*l0, pads absorb OOB).
// Fragment reads shift +4 vs the old m-indexing: Xs[pl*1088 + ci*272 + 4 + 2*lrel].
// W tiles keep the rule-21 swizzle: source seg ^= (row>>1)&3; read seg ^= (cl>>1)&3.

// ---------------- conv2 via f16 3-product MFMA: A=W (m=co), B=X windows (n=l) -------
__global__ __launch_bounds__(256, 2) void conv2_mfma_kernel(
    const _Float16* __restrict__ xin, const _Float16* __restrict__ WH,
    const _Float16* __restrict__ WL, const float* __restrict__ bias,
    _Float16* __restrict__ xout) {
    __shared__ _Float16 Xs[2176];
    __shared__ _Float16 WsH[128 * 32], WsL[128 * 32];
    const int tid = threadIdx.x;
    const int wave = tid >> 6;
    const int lane = tid & 63;
    const int wm = wave >> 1, wn = wave & 1;
    const int q  = lane >> 4;
    const int cl = lane & 15;
    const int l0  = blockIdx.x * 128;
    const int co0 = blockIdx.y * 128;
    const int b   = blockIdx.z;

    const int wrow  = lane >> 2;
    const int wseg  = lane & 3;
    const int wsoff = (wseg ^ ((wrow >> 1) & 3)) * 8;   // swizzled source offset (halfs)
    const int rq    = (q ^ ((cl >> 1) & 3)) * 8;        // swizzled read offset (halfs)

    // X seg decomposition (this thread's seg = tid; tail segs 256..271 on lanes 0..15)
    const int pl0 = (tid >= 136) ? 1 : 0;
    const int r0  = tid - pl0 * 136;
    const int ci0 = r0 / 34;
    const int sg0 = r0 - ci0 * 34;
    const _Float16* xb = xin + (size_t)b * C1V * R1P;

    floatx4 acc[4][4];
#pragma unroll
    for (int a = 0; a < 4; ++a)
#pragma unroll
        for (int n = 0; n < 4; ++n) acc[a][n] = (floatx4){0.f, 0.f, 0.f, 0.f};

    for (int ch = 0; ch < 32; ++ch) {
        __syncthreads();
        {   // X: 272 segs via global_load_lds (no VALU conversion)
            const _Float16* gx = xb + (size_t)(ch * 4 + ci0) * R1P + pl0 * P1P + 2 * l0 + sg0 * 8;
            gload_lds16(gx, (char*)Xs + (tid & ~63) * 16);
            if (tid < 16) {  // tail: pl=1, ci=3, sg=18+tid
                const _Float16* gt = xb + (size_t)(ch * 4 + 3) * R1P + P1P + 2 * l0 + (18 + tid) * 8;
                gload_lds16(gt, (char*)Xs + 4096);
            }
        }
        const int k0 = ch * 32;
        for (int g = wave; g < 8; g += 4) {
            const _Float16* gh = WH + (size_t)(co0 + g * 16 + wrow) * 1024 + k0 + wsoff;
            const _Float16* gl = WL + (size_t)(co0 + g * 16 + wrow) * 1024 + k0 + wsoff;
            gload_lds16(gh, (char*)WsH + g * 1024);
            gload_lds16(gl, (char*)WsL + g * 1024);
        }
        asm volatile("s_waitcnt vmcnt(0)" ::: "memory");
        __syncthreads();

        half8 awh[4], awl[4], bxh[4], bxl[4];
#pragma unroll
        for (int a = 0; a < 4; ++a) {
            const int ro = (wm * 64 + a * 16 + cl) * 32 + rq;
            awh[a] = *(const half8*)&WsH[ro];
            awl[a] = *(const half8*)&WsL[ro];
        }
#pragma unroll
        for (int n = 0; n < 4; ++n) {
            const int lrel = wn * 64 + n * 16 + cl;
            bxh[n] = lds_read_half8_a4(&Xs[q * 272 + 4 + 2 * lrel]);
            bxl[n] = lds_read_half8_a4(&Xs[1088 + q * 272 + 4 + 2 * lrel]);
        }
#pragma unroll
        for (int a = 0; a < 4; ++a)
#pragma unroll
            for (int n = 0; n < 4; ++n) {
                acc[a][n] = __builtin_amdgcn_mfma_f32_16x16x32_f16(awh[a], bxh[n], acc[a][n], 0, 0, 0);
                acc[a][n] = __builtin_amdgcn_mfma_f32_16x16x32_f16(awl[a], bxh[n], acc[a][n], 0, 0, 0);
                acc[a][n] = __builtin_amdgcn_mfma_f32_16x16x32_f16(awh[a], bxl[n], acc[a][n], 0, 0, 0);
            }
    }

    float bv[4][4];
#pragma unroll
    for (int a = 0; a < 4; ++a)
#pragma unroll
        for (int r = 0; r < 4; ++r) bv[a][r] = bias[co0 + wm * 64 + a * 16 + q * 4 + r];
#pragma unroll
    for (int a = 0; a < 4; ++a)
#pragma unroll
        for (int n = 0; n < 4; ++n) {
            const int l = l0 + wn * 64 + n * 16 + cl;
#pragma unroll
            for (int r = 0; r < 4; ++r) {
                const int co = co0 + wm * 64 + a * 16 + q * 4 + r;
                float vv = fmaxf(acc[a][n][r] * (1.f / 1048576.f) + bv[a][r], 0.f);
                float s = vv * 1024.f;               // pre-scaled hi/lo for conv3 staging
                _Float16 h  = (_Float16)s;
                _Float16 lo = (_Float16)(s - (float)h);
                size_t o = (size_t)(b * C2V + co) * R2P + 8 + l;
                xout[o] = h;
                xout[o + P2P] = lo;
            }
        }
}

// ---------------- conv3 via f16 3-product MFMA: A=X windows (m=l), B=W (n=co) -------
__global__ __launch_bounds__(256, 2) void conv3_mfma_kernel(
    const _Float16* __restrict__ xin, const _Float16* __restrict__ WH,
    const _Float16* __restrict__ WL, const float* __restrict__ bias,
    _Float16* __restrict__ outh) {
    __shared__ _Float16 Xs[2176];
    __shared__ _Float16 WsH[128 * 32], WsL[128 * 32];
    const int tid = threadIdx.x;
    const int wave = tid >> 6;
    const int lane = tid & 63;
    const int wm = wave >> 1, wn = wave & 1;
    const int q  = lane >> 4;
    const int cl = lane & 15;
    const int l0  = blockIdx.x * 128;
    const int co0 = blockIdx.y * 128;
    const int b   = blockIdx.z;

    const int wrow  = lane >> 2;
    const int wseg  = lane & 3;
    const int wsoff = (wseg ^ ((wrow >> 1) & 3)) * 8;
    const int rq    = (q ^ ((cl >> 1) & 3)) * 8;

    const int pl0 = (tid >= 136) ? 1 : 0;
    const int r0  = tid - pl0 * 136;
    const int ci0 = r0 / 34;
    const int sg0 = r0 - ci0 * 34;
    const _Float16* xb = xin + (size_t)b * C2V * R2P;

    floatx4 acc[4][4];
#pragma unroll
    for (int a = 0; a < 4; ++a)
#pragma unroll
        for (int n = 0; n < 4; ++n) acc[a][n] = (floatx4){0.f, 0.f, 0.f, 0.f};

    for (int ch = 0; ch < 64; ++ch) {
        __syncthreads();
        {
            const _Float16* gx = xb + (size_t)(ch * 4 + ci0) * R2P + pl0 * P2P + 2 * l0 + sg0 * 8;
            gload_lds16(gx, (char*)Xs + (tid & ~63) * 16);
            if (tid < 16) {
                const _Float16* gt = xb + (size_t)(ch * 4 + 3) * R2P + P2P + 2 * l0 + (18 + tid) * 8;
                gload_lds16(gt, (char*)Xs + 4096);
            }
        }
        const int k0 = ch * 32;
        for (int g = wave; g < 8; g += 4) {
            const _Float16* gh = WH + (size_t)(co0 + g * 16 + wrow) * 2048 + k0 + wsoff;
            const _Float16* gl = WL + (size_t)(co0 + g * 16 + wrow) * 2048 + k0 + wsoff;
            gload_lds16(gh, (char*)WsH + g * 1024);
            gload_lds16(gl, (char*)WsL + g * 1024);
        }
        asm volatile("s_waitcnt vmcnt(0)" ::: "memory");
        __syncthreads();

        half8 axh[4], axl[4], bwh[4], bwl[4];
#pragma unroll
        for (int a = 0; a < 4; ++a) {
            const int lrel = wm * 64 + a * 16 + cl;
            axh[a] = lds_read_half8_a4(&Xs[q * 272 + 4 + 2 * lrel]);
            axl[a] = lds_read_half8_a4(&Xs[1088 + q * 272 + 4 + 2 * lrel]);
        }
#pragma unroll
        for (int n = 0; n < 4; ++n) {
            const int ro = (wn * 64 + n * 16 + cl) * 32 + rq;
            bwh[n] = *(const half8*)&WsH[ro];
            bwl[n] = *(const half8*)&WsL[ro];
        }
#pragma unroll
        for (int a = 0; a < 4; ++a)
#pragma unroll
            for (int n = 0; n < 4; ++n) {
                acc[a][n] = __builtin_amdgcn_mfma_f32_16x16x32_f16(axh[a], bwh[n], acc[a][n], 0, 0, 0);
                acc[a][n] = __builtin_amdgcn_mfma_f32_16x16x32_f16(axl[a], bwh[n], acc[a][n], 0, 0, 0);
                acc[a][n] = __builtin_amdgcn_mfma_f32_16x16x32_f16(axh[a], bwl[n], acc[a][n], 0, 0, 0);
            }
    }

    float bv[4];
#pragma unroll
    for (int n = 0; n < 4; ++n) bv[n] = bias[co0 + wn * 64 + n * 16 + cl];
#pragma unroll
    for (int a = 0; a < 4; ++a)
#pragma unroll
        for (int n = 0; n < 4; ++n) {
            const int co = co0 + wn * 64 + n * 16 + cl;
#pragma unroll
            for (int r = 0; r < 4; ++r) {
                const int l = l0 + wm * 64 + a * 16 + q * 4 + r;
                float f = acc[a][n][r] * (1.f / 1048576.f) + bv[n];
                float s = f * 1024.f;
                _Float16 h = (_Float16)s;
                _Float16 lo = (_Float16)(s - (float)h);
                _Float16* dst = outh + ((size_t)b * L3V + l) * 1024 + co;
                dst[0] = h;
                dst[512] = lo;
            }
        }
}

// ---------------- fused codebook prep: rowsq*2^19 + x1024 hi/lo f16 split ----------
__global__ void cbprep_kernel(const float* __restrict__ cb, _Float16* __restrict__ y,
                              float* __restrict__ c2p) {
    const int r = blockIdx.x;
    const int lane = threadIdx.x;  // 64
    const float* row = cb + (size_t)r * 512;
    float4 a = *(const float4*)&row[lane * 8];
    float4 c = *(const float4*)&row[lane * 8 + 4];
    float s = a.x * a.x + a.y * a.y + a.z * a.z + a.w * a.w
            + c.x * c.x + c.y * c.y + c.z * c.z + c.w * c.w;
#pragma unroll
    for (int off = 32; off > 0; off >>= 1) s += __shfl_down(s, off, 64);
    if (lane == 0) c2p[r] = s * 524288.f;  // 2^19

    const float e[8] = {a.x, a.y, a.z, a.w, c.x, c.y, c.z, c.w};
    half8 hv, lv;
#pragma unroll
    for (int i = 0; i < 8; ++i) {
        float v = e[i] * 1024.f;
        _Float16 h = (_Float16)v;
        hv[i] = h;
        lv[i] = (_Float16)(v - (float)h);
    }
    *(half8*)(y + (size_t)r * 1024 + lane * 8) = hv;
    *(half8*)(y + (size_t)r * 1024 + 512 + lane * 8) = lv;
}

// ---------------- MFMA cross-GEMM + fused argmin, 256l x 256v, 4-phase schedule ----
// (R6-verified; unchanged)
__global__ __launch_bounds__(512, 2) void cross_mfma_kernel(
    const _Float16* __restrict__ Af, const _Float16* __restrict__ Bf,
    const float* __restrict__ c2p,
    int* __restrict__ tok_i, float* __restrict__ tok_f) {

    __shared__ _Float16 AsH[2][8192], AsL[2][8192];   // 16 KB per plane per buf
    __shared__ _Float16 BsH[2][8192], BsL[2][8192];   // 16 KB per plane per buf
    __shared__ float c2s[2048];
    __shared__ float slotv[2][256];
    __shared__ int   sloti[2][256];

    const int tid  = threadIdx.x;
    const int w    = tid >> 6;        // 0..7
    const int lane = tid & 63;
    const int wm = w >> 1;            // 0..3: 64-row band
    const int wn = w & 1;             // 0..1: 128-col band
    const int q  = lane >> 4;
    const int cl = lane & 15;

    const int l0 = blockIdx.x * 256;
    const int k  = blockIdx.y;
    const int b  = blockIdx.z;

    const _Float16* Ab = Af + (size_t)(b * L3V + l0) * 1024;
    const _Float16* Bb = Bf + (size_t)k * VOCABV * 1024;

    // prologue: c2 -> LDS; slot init
    {
        float4 cv = *(const float4*)&c2p[k * VOCABV + tid * 4];
        *(float4*)&c2s[tid * 4] = cv;
    }
    if (tid < 256) {
        slotv[0][tid] = -3.4e38f; slotv[1][tid] = -3.4e38f;
        sloti[0][tid] = 0;        sloti[1][tid] = 0;
    }

    // staging geometry (per-lane constants)
    const int arow  = w * 16 + (lane >> 2);            // A: row within 128-half
    const int bg    = (w >> 1) & 1;                    // B: wn-group
    const int bj    = (w & 1) * 16 + (lane >> 2);      // B: row within 32-group
    const int bpl   = w >> 2;                          // B: plane (0=hi,1=lo)
    const int sswz8 = ((lane & 3) ^ ((lane >> 3) & 3)) * 8;  // swizzled src seg (halfs)
    const int brq   = (q ^ ((cl >> 1) & 3)) * 8;       // swizzled read seg (halfs)

#define STAGE_A(NXT, KON, PL, H) do { \
    const _Float16* s_ = Ab + (size_t)((H) * 128 + arow) * 1024 + (PL) * 512 + (KON) + sswz8; \
    gload_lds16(s_, ((PL) ? (char*)&AsL[NXT][0] : (char*)&AsH[NXT][0]) \
                     + (H) * 8192 + w * 1024 + lane * 16); \
} while (0)
#define STAGE_B(NXT, VTN, KON, C) do { \
    const _Float16* s_ = Bb + (size_t)((VTN) * 256 + 128 * bg + 32 * (C) + bj) * 1024 \
                         + bpl * 512 + (KON) + sswz8; \
    gload_lds16(s_, (bpl ? (char*)&BsL[NXT][0] : (char*)&BsH[NXT][0]) \
                     + (C) * 4096 + (w & 3) * 1024 + lane * 16); \
} while (0)

    floatx4 acc[4][8];
    half8 ah[4], al[4];
    int cur = 0;

    STAGE_A(0, 0, 0, 0); STAGE_A(0, 0, 0, 1);
    STAGE_A(0, 0, 1, 0); STAGE_A(0, 0, 1, 1);
    STAGE_B(0, 0, 0, 0); STAGE_B(0, 0, 0, 1);
    STAGE_B(0, 0, 0, 2); STAGE_B(0, 0, 0, 3);

#define PHASE(P, VMC) do { \
    asm volatile("s_waitcnt vmcnt(" #VMC ")" ::: "memory"); \
    __builtin_amdgcn_s_barrier(); \
    if ((P) == 0) { \
        _Pragma("unroll") \
        for (int mt = 0; mt < 4; ++mt) { \
            const int aro = (wm * 64 + mt * 16 + cl) * 32 + brq; \
            ah[mt] = *(const half8*)&AsH[cur][aro]; \
            al[mt] = *(const half8*)&AsL[cur][aro]; \
        } \
    } \
    const int bro0_ = (P) * 2048 + wn * 1024 + cl * 32 + brq; \
    const int bro1_ = bro0_ + 512; \
    half8 bh0_ = *(const half8*)&BsH[cur][bro0_]; \
    half8 bl0_ = *(const half8*)&BsL[cur][bro0_]; \
    half8 bh1_ = *(const half8*)&BsH[cur][bro1_]; \
    half8 bl1_ = *(const half8*)&BsL[cur][bro1_]; \
    if ((P) == 0)      { STAGE_A(nxt, kon, 0, 0); STAGE_A(nxt, kon, 0, 1); } \
    else if ((P) == 1) { STAGE_A(nxt, kon, 1, 0); STAGE_A(nxt, kon, 1, 1); } \
    else if ((P) == 2) { STAGE_B(nxt, vtn, kon, 0); STAGE_B(nxt, vtn, kon, 1); } \
    else               { STAGE_B(nxt, vtn, kon, 2); STAGE_B(nxt, vtn, kon, 3); } \
    asm volatile("s_waitcnt lgkmcnt(0)" ::: "memory"); \
    __builtin_amdgcn_sched_barrier(0); \
    __builtin_amdgcn_s_setprio(1); \
    _Pragma("unroll") \
    for (int mt = 0; mt < 4; ++mt) { \
        acc[mt][2*(P)]   = __builtin_amdgcn_mfma_f32_16x16x32_f16(ah[mt], bh0_, acc[mt][2*(P)], 0, 0, 0); \
        acc[mt][2*(P)]   = __builtin_amdgcn_mfma_f32_16x16x32_f16(al[mt], bh0_, acc[mt][2*(P)], 0, 0, 0); \
        acc[mt][2*(P)]   = __builtin_amdgcn_mfma_f32_16x16x32_f16(ah[mt], bl0_, acc[mt][2*(P)], 0, 0, 0); \
        acc[mt][2*(P)+1] = __builtin_amdgcn_mfma_f32_16x16x32_f16(ah[mt], bh1_, acc[mt][2*(P)+1], 0, 0, 0); \
        acc[mt][2*(P)+1] = __builtin_amdgcn_mfma_f32_16x16x32_f16(al[mt], bh1_, acc[mt][2*(P)+1], 0, 0, 0); \
        acc[mt][2*(P)+1] = __builtin_amdgcn_mfma_f32_16x16x32_f16(ah[mt], bl1_, acc[mt][2*(P)+1], 0, 0, 0); \
    } \
    __builtin_amdgcn_s_setprio(0); \
    __builtin_amdgcn_sched_barrier(0); \
} while (0)

#pragma unroll 1
    for (int t = 0; t < 128; ++t) {
        const int nxt = cur ^ 1;
        const int tn  = t + 1;
        const int vtn = tn >> 4;                 // 8 at t=127: benign over-read
        const int kon = (tn & 15) << 5;
        const int vt  = t >> 4;

        if ((t & 15) == 0) {
#pragma unroll
            for (int mt = 0; mt < 4; ++mt)
#pragma unroll
                for (int nt = 0; nt < 8; ++nt) acc[mt][nt] = (floatx4){0.f, 0.f, 0.f, 0.f};
        }

        { PHASE(0, 3); }
        { PHASE(1, 4); }
        { PHASE(2, 5); }
        { PHASE(3, 6); }
        cur = nxt;

        if ((t & 15) == 15) {
            float c2v[8];
#pragma unroll
            for (int nt = 0; nt < 8; ++nt)
                c2v[nt] = c2s[vt * 256 + wn * 128 + nt * 16 + cl];
#pragma unroll
            for (int mt = 0; mt < 4; ++mt)
#pragma unroll
                for (int r = 0; r < 4; ++r) {
                    float bv = acc[mt][0][r] - c2v[0];
                    int   bi = vt * 256 + wn * 128 + cl;
#pragma unroll
                    for (int nt = 1; nt < 8; ++nt) {
                        float m = acc[mt][nt][r] - c2v[nt];
                        int   vi = vt * 256 + wn * 128 + nt * 16 + cl;
                        if (m > bv) { bv = m; bi = vi; }
                    }
#pragma unroll
                    for (int msk = 1; msk < 16; msk <<= 1) {
                        float ov = __shfl_xor(bv, msk, 64);
                        int   oi = __shfl_xor(bi, msk, 64);
                        if (ov > bv || (ov == bv && oi < bi)) { bv = ov; bi = oi; }
                    }
                    if (cl == 0) {
                        const int row = wm * 64 + mt * 16 + q * 4 + r;
                        float cur_v = slotv[wn][row];
                        int   ci  = sloti[wn][row];
                        if (bv > cur_v || (bv == cur_v && bi < ci)) {
                            slotv[wn][row] = bv;
                            sloti[wn][row] = bi;
                        }
                    }
                }
        }
    }
#undef PHASE
#undef STAGE_A
#undef STAGE_B

    __syncthreads();
    if (tid < 256) {
        float v0 = slotv[0][tid], v1 = slotv[1][tid];
        int   i0 = sloti[0][tid], i1 = sloti[1][tid];
        bool t1 = (v1 > v0);  // wn=1 indices always larger: ties keep wn=0
        int best = t1 ? i1 : i0;
        const int n = (b * KCB + k) * L3V + l0 + tid;
        tok_i[n] = best;
        tok_f[n] = (float)best;
    }
}

// ---------------- embedding mean over 4 codebooks ----------------
__global__ void emb_kernel(const int* __restrict__ tokens, const float* __restrict__ E,
                           float* __restrict__ out) {
    const int l = blockIdx.x;
    const int b = blockIdx.y;
    const int h4 = threadIdx.x * 4;
    const int t0 = tokens[((size_t)(b * KCB + 0)) * L3V + l];
    const int t1 = tokens[((size_t)(b * KCB + 1)) * L3V + l];
    const int t2 = tokens[((size_t)(b * KCB + 2)) * L3V + l];
    const int t3 = tokens[((size_t)(b * KCB + 3)) * L3V + l];
    const float4 e0 = *(const float4*)&E[(size_t)t0 * 512 + h4];
    const float4 e1 = *(const float4*)&E[(size_t)t1 * 512 + h4];
    const float4 e2 = *(const float4*)&E[(size_t)t2 * 512 + h4];
    const float4 e3 = *(const float4*)&E[(size_t)t3 * 512 + h4];
    float4 r;
    r.x = (e0.x + e1.x + e2.x + e3.x) * 0.25f;
    r.y = (e0.y + e1.y + e2.y + e3.y) * 0.25f;
    r.z = (e0.z + e1.z + e2.z + e3.z) * 0.25f;
    r.w = (e0.w + e1.w + e2.w + e3.w) * 0.25f;
    *(float4*)&out[((size_t)b * L3V + l) * 512 + h4] = r;
}

extern "C" void kernel_launch(void* const* d_in, const int* in_sizes, int n_in,
                              void* d_out, int out_size, void* d_ws, size_t ws_size,
                              hipStream_t stream) {
    const float* audio = (const float*)d_in[0];
    const float* w1 = (const float*)d_in[1];
    const float* b1 = (const float*)d_in[2];
    const float* w2 = (const float*)d_in[3];
    const float* b2 = (const float*)d_in[4];
    const float* w3 = (const float*)d_in[5];
    const float* b3 = (const float*)d_in[6];
    const float* cb = (const float*)d_in[7];
    const float* E  = (const float*)d_in[8];

    float* out_tok = (float*)d_out;
    float* out_emb = out_tok + (size_t)B_ * KCB * L3V;

    float* ws = (float*)d_ws;
    size_t off = 0;
    // x1: hi/lo f16 planes, B*C1V rows x 2*(L1V+16) halfs = B*C1V*(L1V+16) floats.
    // Also reused as Afh (conv3 out, 16.78M halfs <= 16.79M) after conv2 consumes x1.
    float* x1f = ws + off; off += (size_t)B_ * C1V * (L1V + 16);
    // x2: hi/lo f16 planes for conv2 out; reused as Bfh after conv3 consumes x2
    // (stream-ordered: conv3 -> cbprep -> cross).
    float* x2f = ws + off; off += (size_t)B_ * C2V * (L2V + 16);
    float* w2h_f = ws + off; off += (size_t)C2V * (C1V * 8) / 2;
    float* w2l_f = ws + off; off += (size_t)C2V * (C1V * 8) / 2;
    float* w3h_f = ws + off; off += (size_t)C3V * (C2V * 8) / 2;
    float* w3l_f = ws + off; off += (size_t)C3V * (C2V * 8) / 2;
    float* c2p = ws + off; off += (size_t)KCB * VOCABV;
    int*   tok = (int*)(ws + off); off += (size_t)B_ * KCB * L3V;

    _Float16* X1  = (_Float16*)x1f;
    _Float16* X2  = (_Float16*)x2f;
    _Float16* Afh = (_Float16*)x1f;   // conv3 writes over x1 (dead after conv2)
    _Float16* Bfh = (_Float16*)x2f;   // cbprep writes over x2 (dead after conv3)
    _Float16* W2H = (_Float16*)w2h_f; _Float16* W2L = (_Float16*)w2l_f;
    _Float16* W3H = (_Float16*)w3h_f; _Float16* W3L = (_Float16*)w3l_f;

    padzero_kernel<<<24, 256, 0, stream>>>(X1, X2);

    wsplit_kernel<<<(C2V * C1V + 255) / 256, 256, 0, stream>>>(w2, W2H, W2L, C1V, C2V);
    wsplit_kernel<<<(C3V * C2V + 255) / 256, 256, 0, stream>>>(w3, W3H, W3L, C2V, C3V);

    conv1_kernel<<<dim3(L1V / 256, C1V, B_), 256, 0, stream>>>(audio, w1, b1, X1);

    conv2_mfma_kernel<<<dim3(L2V / 128, C2V / 128, B_), 256, 0, stream>>>(
        X1, W2H, W2L, b2, X2);

    conv3_mfma_kernel<<<dim3(L3V / 128, C3V / 128, B_), 256, 0, stream>>>(
        X2, W3H, W3L, b3, Afh);

    cbprep_kernel<<<KCB * VOCABV, 64, 0, stream>>>(cb, Bfh, c2p);

    cross_mfma_kernel<<<dim3(L3V / 256, KCB, B_), 512, 0, stream>>>(
        Afh, Bfh, c2p, tok, out_tok);

    emb_kernel<<<dim3(L3V, B_), 128, 0, stream>>>(tok, E, out_emb);
}